// Round 3
// baseline (178.910 us; speedup 1.0000x reference)
//
#include <hip/hip_runtime.h>
#include <hip/hip_bf16.h>
#include <math.h>

// Shapes (fixed): B=8, C=16, R=16, M=N=512. K of both real GEMMs = 1024.
//
// Pipeline (7 launches):
//   k_prep  : t=einsum, (d,e) per (b,c), alpha=(-S0,-S1), CC
//   k_trans : Wi->A2 bf16 [m1][2m+c]; Wj->B5T bf16 [n1][2n+c] (*alpha, -im);
//             base->baseT fp32 [n][m]
//   k_mimj  : rank-16 factors mi_s/mj_s (fp32)
//   k_gram  : EXACT mean/std of mod_r from 16x16 Gram matrices (rank-16 algebra)
//   k_bmod  : fused: rank-16 outer product + normalize + *baseT -> B2T bf16
//   k_gemm<128,true,true>  : G1X = A2 . B2T^T   (512x1024x1024, bf16 out)
//   k_gemm<64,false,false> : out = CC + G1X . B5T^T (512x512x1024, fp32 out)
//
// GEMM structure: 64x128 tiles (512 blocks = 2/CU), per-batch operand staged
// in LDS via global_load_lds w/ XOR swizzle; SHARED operand (A2/B5T, 1MB,
// L2-hot) fragments loaded direct global->VGPR, issued before the barrier so
// they complete during the same vmcnt(0) drain.

#define WS_T       0
#define WS_DE      1024
#define WS_SCAL    1280
#define WS_STATS   1296
#define WS_MIS     4096        // [8][16][512][2] fp32
#define WS_MJS     135168
#define WS_BASET   266240      // [512][512][2] fp32
#define WS_A2      790528      // 512*1024 bf16
#define WS_B5T     1052672     // 512*1024 bf16
#define WS_G1X     1314816     // 8*512*1024 bf16
#define WS_B2T     3411968     // 8*1024*1024 bf16 ; end 7,606,272 floats (~30 MB)

typedef __attribute__((ext_vector_type(8))) short short8;
typedef __attribute__((ext_vector_type(4))) float f32x4;

__device__ __forceinline__ unsigned short f2bf(float f) {
    unsigned int u = __float_as_uint(f);
    u = (u + 0x7FFFu + ((u >> 16) & 1u)) >> 16;
    return (unsigned short)u;
}
__device__ __forceinline__ unsigned int pack2bf(float a, float b) {
    return (unsigned int)f2bf(a) | ((unsigned int)f2bf(b) << 16);
}
__device__ __forceinline__ void load_lds16(const unsigned int* g, unsigned short* l) {
    __builtin_amdgcn_global_load_lds((const __attribute__((address_space(1))) unsigned int*)g,
                                     (__attribute__((address_space(3))) unsigned int*)l, 16, 0, 0);
}

// ---------------------------------------------------------------------------
__global__ void k_prep(const float* __restrict__ x, const float* __restrict__ mt,
                       const float* __restrict__ inv, const float* __restrict__ td,
                       const float* __restrict__ rd, float* __restrict__ ws) {
    float* tbuf = ws + WS_T;
    float* de   = ws + WS_DE;
    float* scal = ws + WS_SCAL;
    int tid = threadIdx.x;
    for (int i = tid; i < 1024; i += 256) {
        int b = i >> 7, k = (i >> 5) & 3, l = i & 31;
        float s = 0.f;
        for (int c = 0; c < 16; c++) s += x[b * 16 + c] * mt[(k * 16 + c) * 32 + l];
        tbuf[i] = s;
    }
    __syncthreads();
    if (tid < 128) {
        int b = tid >> 4, c = tid & 15;
        float i0 = inv[2 * c], i1 = inv[2 * c + 1];
        float z0 = tbuf[(b * 4 + 1) * 32 + 2 * c], z1 = tbuf[(b * 4 + 1) * 32 + 2 * c + 1];
        de[tid * 2]     = i0 * z0 + i1 * z1;
        de[tid * 2 + 1] = i0 * z1 - i1 * z0;
    }
    if (tid == 0) {
        float S0 = 0.f, S1 = 0.f, CCv = 0.f;
        for (int c = 0; c < 16; c++) {
            float r0 = rd[2 * c], r1 = rd[2 * c + 1];
            float t0 = td[2 * c], t1 = td[2 * c + 1];
            S0 += r0; S1 += r1;
            CCv += t1 * r1 - t0 * r0;
        }
        scal[0] = -S0; scal[1] = -S1; scal[2] = CCv;
    }
}

// ---------------------------------------------------------------------------
__global__ void k_trans(const float* __restrict__ Wi, const float* __restrict__ Wj,
                        const float* __restrict__ base, float* __restrict__ ws) {
    __shared__ float2 tile[32][33];
    int mode = blockIdx.z;
    int bx = blockIdx.x, by = blockIdx.y;
    int tx = threadIdx.x & 31, ty = threadIdx.x >> 5;
    const float* src = (mode == 0) ? Wi : (mode == 1) ? Wj : base;
    for (int i = 0; i < 4; i++) {
        int rIn = by * 32 + ty + i * 8;
        int cIn = bx * 32 + tx;
        tile[ty + i * 8][tx] = *(const float2*)(src + ((size_t)rIn * 512 + cIn) * 2);
    }
    __syncthreads();
    if (mode == 0) {
        unsigned int* A2u = (unsigned int*)(ws + WS_A2);
        for (int i = 0; i < 4; i++) {
            int rOut = bx * 32 + ty + i * 8;
            int cOut = by * 32 + tx;
            float2 v = tile[tx][ty + i * 8];
            A2u[(size_t)rOut * 512 + cOut] = pack2bf(v.x, v.y);
        }
    } else if (mode == 1) {
        const float* scal = ws + WS_SCAL;
        float ar = scal[0], ai = scal[1];
        unsigned int* B5u = (unsigned int*)(ws + WS_B5T);
        for (int i = 0; i < 4; i++) {
            int rOut = bx * 32 + ty + i * 8;
            int cOut = by * 32 + tx;
            float2 v = tile[tx][ty + i * 8];
            float wr = ar * v.x - ai * v.y;
            float wi = ar * v.y + ai * v.x;
            B5u[(size_t)rOut * 512 + cOut] = pack2bf(wr, -wi);
        }
    } else {
        float* baseT = ws + WS_BASET;
        for (int i = 0; i < 4; i++) {
            int rOut = bx * 32 + ty + i * 8;
            int cOut = by * 32 + tx;
            *(float2*)(baseT + ((size_t)rOut * 512 + cOut) * 2) = tile[tx][ty + i * 8];
        }
    }
}

// ---------------------------------------------------------------------------
// k_mimj: blocks 0..255 compute mi_s; 256..511 compute mj_s
__global__ void k_mimj(const float* __restrict__ mod_i, const float* __restrict__ mod_j,
                       const float* __restrict__ inv, float* __restrict__ ws) {
    const float* tbuf = ws + WS_T;
    int blk = blockIdx.x;
    if (blk < 256) {
        const float* de = ws + WS_DE;
        float* mi_s     = ws + WS_MIS;
        int id = blk * 256 + threadIdx.x;
        int b = id >> 13, rm = id & 8191;
        float acc0 = 0.f, acc1 = 0.f;
        for (int c = 0; c < 16; c++) {
            const float* p = mod_i + (((size_t)c * 8192) + rm) * 2;
            float t00 = tbuf[(b * 4 + 0) * 32 + 2 * c];
            float t01 = tbuf[(b * 4 + 0) * 32 + 2 * c + 1];
            float d = de[(b * 16 + c) * 2], e = de[(b * 16 + c) * 2 + 1];
            float A0 = p[0] + t00, A1 = p[1] + t01;
            acc0 += d * A0 - e * A1;
            acc1 += e * A0 + d * A1;
        }
        float* dst = mi_s + ((size_t)b * 8192 + rm) * 2;
        dst[0] = acc0; dst[1] = acc1;
    } else {
        float* mj_s = ws + WS_MJS;
        int id = (blk - 256) * 256 + threadIdx.x;
        int b = id >> 13, rn = id & 8191;
        float acc0 = 0.f, acc1 = 0.f;
        for (int c = 0; c < 16; c++) {
            const float* p = mod_j + (((size_t)c * 8192) + rn) * 2;
            float t20 = tbuf[(b * 4 + 2) * 32 + 2 * c];
            float t21 = tbuf[(b * 4 + 2) * 32 + 2 * c + 1];
            float z0  = tbuf[(b * 4 + 3) * 32 + 2 * c];
            float z1  = tbuf[(b * 4 + 3) * 32 + 2 * c + 1];
            float A0 = p[0] + t20, A1 = p[1] + t21;
            float w0 = -z0 * A0 + z1 * A1;
            float w1 =  z1 * A0 + z0 * A1;
            float i0 = inv[2 * c], i1 = inv[2 * c + 1];
            float den = w0 * w0 + w1 * w1;
            acc0 += (i0 * w0 + i1 * w1) / den;
            acc1 += (i0 * w1 - i1 * w0) / den;
        }
        float* dst = mj_s + ((size_t)b * 8192 + rn) * 2;
        dst[0] = acc0; dst[1] = acc1;
    }
}

// ---------------------------------------------------------------------------
// k_gram: exact stats of mod_r = Re(sum_r mj[r,n]*mi[r,m]) via Gram matrices.
//   sum   = Re(sum_r beta_r * a_r),  a=colsum(mi), beta=colsum(mj)
//   sumsq = 0.5*sum_{rr'}[Re(Su*Sv) + Re(Tu*Tv)],  S=plain gram, T=conj gram
__global__ __launch_bounds__(256) void k_gram(float* __restrict__ ws) {
    __shared__ float2 Vs[16][130];   // +2 pad: r2-strided reads land 2-way (free)
    __shared__ float2 Us[16][130];
    int b = blockIdx.x, tid = threadIdx.x;
    int r = tid >> 4, r2 = tid & 15;
    const float2* V = (const float2*)(ws + WS_MIS + (size_t)b * 16384);
    const float2* U = (const float2*)(ws + WS_MJS + (size_t)b * 16384);
    float Svr = 0, Svi = 0, Tvr = 0, Tvi = 0;
    float Sur = 0, Sui = 0, Tur = 0, Tui = 0;
    float ar = 0, ai = 0, br = 0, bi = 0;
    for (int h = 0; h < 4; h++) {
        for (int p = 0; p < 8; p++) {
            int f = tid + p * 256;             // 2048 = 16*128
            int rr = f >> 7, mm = f & 127;
            Vs[rr][mm] = V[rr * 512 + h * 128 + mm];
            Us[rr][mm] = U[rr * 512 + h * 128 + mm];
        }
        __syncthreads();
        for (int mm = 0; mm < 128; mm++) {
            float2 v1 = Vs[r][mm], v2 = Vs[r2][mm];
            float2 u1 = Us[r][mm], u2 = Us[r2][mm];
            Svr += v1.x * v2.x - v1.y * v2.y;  Svi += v1.x * v2.y + v1.y * v2.x;
            Tvr += v1.x * v2.x + v1.y * v2.y;  Tvi += v1.y * v2.x - v1.x * v2.y;
            Sur += u1.x * u2.x - u1.y * u2.y;  Sui += u1.x * u2.y + u1.y * u2.x;
            Tur += u1.x * u2.x + u1.y * u2.y;  Tui += u1.y * u2.x - u1.x * u2.y;
            if (r2 == 0) { ar += v1.x; ai += v1.y; br += u1.x; bi += u1.y; }
        }
        __syncthreads();
    }
    float val = (Sur * Svr - Sui * Svi) + (Tur * Tvr - Tui * Tvi);
    float mterm = (r2 == 0) ? (br * ar - bi * ai) : 0.f;
    float* red = (float*)&Vs[0][0];
    red[tid] = val; red[256 + tid] = mterm;
    __syncthreads();
    for (int s = 128; s > 0; s >>= 1) {
        if (tid < s) { red[tid] += red[tid + s]; red[256 + tid] += red[256 + tid + s]; }
        __syncthreads();
    }
    if (tid == 0) {
        double MN = 262144.0;
        double mu = (double)red[256] / MN;
        double sumsq = 0.5 * (double)red[0];
        double var = (sumsq - MN * mu * mu) / (MN - 1.0);
        if (var < 1e-30) var = 1e-30;
        float* stats = ws + WS_STATS;
        stats[b * 2] = (float)mu;
        stats[b * 2 + 1] = (float)(1.0 / sqrt(var));
    }
}

// ---------------------------------------------------------------------------
// k_bmod: fused rank-16 outer product + normalization + base modulation,
// writes B2T bf16 expanded-transposed directly.
__global__ __launch_bounds__(256) void k_bmod(float* __restrict__ ws) {
    const float* mi_s  = ws + WS_MIS;
    const float* mj_s  = ws + WS_MJS;
    const float* baseT = ws + WS_BASET;
    const float* stats = ws + WS_STATS;
    unsigned int* B2T  = (unsigned int*)(ws + WS_B2T);
    int mt = blockIdx.x, nt = blockIdx.y, b = blockIdx.z;
    __shared__ float Ns[16][128];
    __shared__ float Ms[16][128];
    int tid = threadIdx.x, tx = tid & 15, ty = tid >> 4;
    const float* Nb = mj_s + (size_t)b * 16384;
    const float* Mb = mi_s + (size_t)b * 16384;
    int n0 = nt * 64, m0 = mt * 64;
    for (int i = 0; i < 4; i++) {
        int flat = tid + i * 256;
        int col = flat & 63, r = flat >> 6;
        float2 sa = *(const float2*)(Nb + ((size_t)r * 512 + n0 + col) * 2);
        Ns[r][col * 2] = sa.x; Ns[r][col * 2 + 1] = sa.y;
        float2 sb = *(const float2*)(Mb + ((size_t)r * 512 + m0 + col) * 2);
        Ms[r][col * 2] = sb.x; Ms[r][col * 2 + 1] = sb.y;
    }
    __syncthreads();
    float cr[4][4] = {}, ci[4][4] = {};
    for (int r = 0; r < 16; r++) {
        float nr[4], ni[4], mr[4], mi_[4];
        for (int i = 0; i < 4; i++) { nr[i] = Ns[r][(ty * 4 + i) * 2]; ni[i] = Ns[r][(ty * 4 + i) * 2 + 1]; }
        for (int j = 0; j < 4; j++) { mr[j] = Ms[r][(tx * 4 + j) * 2]; mi_[j] = Ms[r][(tx * 4 + j) * 2 + 1]; }
        for (int i = 0; i < 4; i++)
            for (int j = 0; j < 4; j++) {
                cr[i][j] += nr[i] * mr[j] - ni[i] * mi_[j];
                ci[i][j] += nr[i] * mi_[j] + ni[i] * mr[j];
            }
    }
    float mu = stats[b * 2], rstd = stats[b * 2 + 1];
    unsigned int* Bb = B2T + (size_t)b * 524288;
    for (int i = 0; i < 4; i++) {
        int n = n0 + ty * 4 + i;
        int mcol = m0 + tx * 4;
        const float4* bsp = (const float4*)(baseT + ((size_t)n * 512 + mcol) * 2);
        float4 b01 = bsp[0], b23 = bsp[1];
        float bsr[4] = {b01.x, b01.z, b23.x, b23.z};
        float bsi[4] = {b01.y, b01.w, b23.y, b23.w};
        uint4 w0, w1;
        unsigned int* p0 = (unsigned int*)&w0;
        unsigned int* p1 = (unsigned int*)&w1;
        for (int j = 0; j < 4; j++) {
            float wr = bsr[j] * (1.f + (cr[i][j] - mu) * rstd);
            float wi = bsi[j] * (1.f + ci[i][j]);
            p0[j] = pack2bf(wr, -wi);
            p1[j] = pack2bf(wi, wr);
        }
        *(uint4*)&Bb[(size_t)(2 * n) * 512 + mcol]     = w0;
        *(uint4*)&Bb[(size_t)(2 * n + 1) * 512 + mcol] = w1;
    }
}

// ---------------------------------------------------------------------------
// MFMA GEMM: C[512 x ngl] = A[512 x 1024] . BT[ngl x 1024]^T per batch.
// TM=64, TN in {128,64}; 4 waves as 2x2, wave-tile 32 x TN/2.
// STAGE_B: per-batch BT staged in LDS, shared A direct; else A staged, BT direct.
template <int TN, bool STAGE_B, bool OUT_BF16>
__global__ __launch_bounds__(256) void k_gemm(const unsigned short* __restrict__ Aall,
                                              const unsigned short* __restrict__ BTall,
                                              void* __restrict__ Call,
                                              const float* __restrict__ scal,
                                              size_t a_bs, size_t bt_bs, size_t c_bs,
                                              int ngl) {
    constexpr int K = 1024;
    constexpr int WJT = TN / 32;                 // j-subtiles per wave
    constexpr int SROWS = STAGE_B ? TN : 64;     // staged-operand rows
    constexpr int SM1 = SROWS * 64;              // staged bf16 elems per K-tile
    constexpr int SM2 = OUT_BF16 ? 64 * 136 : 0; // epilogue repack
    constexpr int SMEMN = SM1 > SM2 ? SM1 : SM2;
    __shared__ __align__(16) unsigned short smem[SMEMN];

    const int tid = threadIdx.x;
    const int b = blockIdx.z;
    const unsigned short* A  = Aall  + (size_t)b * a_bs;
    const unsigned short* BT = BTall + (size_t)b * bt_bs;
    const unsigned short* Sg = STAGE_B ? BT : A;   // staged side
    const unsigned short* Dg = STAGE_B ? A  : BT;  // direct side
    const int mBase = blockIdx.y * 64;
    const int nBase = blockIdx.x * TN;
    const int sBase = STAGE_B ? nBase : mBase;
    const int wave = tid >> 6, lane = tid & 63;
    const int wm = wave >> 1, wn = wave & 1;
    const int l15 = lane & 15, q = lane >> 4;

    f32x4 acc[2][WJT];
    for (int i = 0; i < 2; i++)
        for (int j = 0; j < WJT; j++) acc[i][j] = (f32x4)0.f;

    for (int k0 = 0; k0 < K; k0 += 64) {
        // stage per-batch operand via global_load_lds (XOR chunk swizzle)
#pragma unroll
        for (int p = 0; p < SROWS * 8 / 256; p++) {
            int flat = tid + p * 256;
            int r = flat >> 3, c = flat & 7;
            int gc = (c ^ (r & 7)) << 3;
            load_lds16((const unsigned int*)(Sg + (size_t)(sBase + r) * K + k0 + gc),
                       &smem[flat << 3]);
        }
        // direct-side frags: issue before barrier, they drain with the same vmcnt
        short8 df[2][2];
#pragma unroll
        for (int ks = 0; ks < 2; ks++)
#pragma unroll
            for (int t = 0; t < 2; t++) {
                int row = STAGE_B ? (mBase + wm * 32 + t * 16 + l15)
                                  : (nBase + wn * (TN / 2) + t * 16 + l15);
                df[ks][t] = *(const short8*)(Dg + (size_t)row * K + k0 + (ks * 4 + q) * 8);
            }
        __syncthreads();
#pragma unroll
        for (int ks = 0; ks < 2; ks++) {
            constexpr int SN = STAGE_B ? WJT : 2;
            short8 sf[SN];
#pragma unroll
            for (int t = 0; t < SN; t++) {
                int sr = (STAGE_B ? wn * (TN / 2) : wm * 32) + t * 16 + l15;
                int sj = (ks * 4 + q) ^ (sr & 7);
                sf[t] = *(const short8*)&smem[sr * 64 + sj * 8];
            }
#pragma unroll
            for (int i = 0; i < 2; i++)
#pragma unroll
                for (int j = 0; j < WJT; j++) {
                    short8 af = STAGE_B ? df[ks][i] : sf[i];
                    short8 bf = STAGE_B ? sf[j] : df[ks][j];
                    acc[i][j] = __builtin_amdgcn_mfma_f32_16x16x32_bf16(af, bf, acc[i][j], 0, 0, 0);
                }
        }
        __syncthreads();
    }

    if constexpr (OUT_BF16) {
#pragma unroll
        for (int i = 0; i < 2; i++) {
            int row0 = wm * 32 + i * 16 + q * 4;
#pragma unroll
            for (int j = 0; j < WJT; j++) {
                int col = wn * (TN / 2) + j * 16 + l15;
#pragma unroll
                for (int r = 0; r < 4; r++)
                    smem[(row0 + r) * 136 + col] = f2bf(acc[i][j][r]);
            }
        }
        __syncthreads();
        unsigned short* C = (unsigned short*)Call + (size_t)b * c_bs;
#pragma unroll
        for (int p = 0; p < TN / 32; p++) {
            int flat = tid + p * 256;
            int r = flat / (TN / 8), c = flat % (TN / 8);
            short8 v = *(const short8*)&smem[r * 136 + c * 8];
            *(short8*)(C + (size_t)(mBase + r) * ngl + nBase + c * 8) = v;
        }
    } else {
        float CC = scal[2];
        float* C = (float*)Call + (size_t)b * c_bs;
#pragma unroll
        for (int i = 0; i < 2; i++) {
            int row0 = mBase + wm * 32 + i * 16 + q * 4;
#pragma unroll
            for (int j = 0; j < WJT; j++) {
                int col = nBase + wn * (TN / 2) + j * 16 + l15;
#pragma unroll
                for (int r = 0; r < 4; r++)
                    C[(size_t)(row0 + r) * ngl + col] = acc[i][j][r] + CC;
            }
        }
    }
}

// ---------------------------------------------------------------------------
extern "C" void kernel_launch(void* const* d_in, const int* in_sizes, int n_in,
                              void* d_out, int out_size, void* d_ws, size_t ws_size,
                              hipStream_t stream) {
    const float* x    = (const float*)d_in[0];
    const float* Wi   = (const float*)d_in[1];
    const float* Wj   = (const float*)d_in[2];
    const float* base = (const float*)d_in[3];
    const float* td   = (const float*)d_in[6];
    const float* rd   = (const float*)d_in[7];
    const float* modi = (const float*)d_in[8];
    const float* modj = (const float*)d_in[9];
    const float* inv  = (const float*)d_in[10];
    const float* mt   = (const float*)d_in[11];
    float* ws  = (float*)d_ws;
    float* out = (float*)d_out;

    unsigned short* A2  = (unsigned short*)(ws + WS_A2);
    unsigned short* B5T = (unsigned short*)(ws + WS_B5T);
    unsigned short* B2T = (unsigned short*)(ws + WS_B2T);
    unsigned short* G1X = (unsigned short*)(ws + WS_G1X);
    const float* scal   = ws + WS_SCAL;

    k_prep<<<1, 256, 0, stream>>>(x, mt, inv, td, rd, ws);
    k_trans<<<dim3(16, 16, 3), 256, 0, stream>>>(Wi, Wj, base, ws);
    k_mimj<<<512, 256, 0, stream>>>(modi, modj, inv, ws);
    k_gram<<<8, 256, 0, stream>>>(ws);
    k_bmod<<<dim3(8, 8, 8), 256, 0, stream>>>(ws);
    k_gemm<128, true, true><<<dim3(8, 8, 8), 256, 0, stream>>>(
        A2, B2T, (void*)G1X, scal, (size_t)0, (size_t)1048576, (size_t)524288, 1024);
    k_gemm<64, false, false><<<dim3(8, 8, 8), 256, 0, stream>>>(
        G1X, B5T, (void*)out, scal, (size_t)524288, (size_t)0, (size_t)262144, 512);
}

// Round 4
// 172.338 us; speedup vs baseline: 1.0381x; 1.0381x over previous
//
#include <hip/hip_runtime.h>
#include <hip/hip_bf16.h>
#include <math.h>

// Shapes (fixed): B=8, C=16, R=16, M=N=512. K of both real GEMMs = 1024.
//
// Pipeline (6 launches):
//   k_trans : Wi->A2 bf16 [m1][2m+c]; Wj->B5T bf16 [n1][2n+c] (*alpha, -im,
//             alpha computed inline from rd); base->baseT fp32 [n][m]
//   k_mimj  : rank-16 factors mi_s/mj_s (fp32); per-block inline prep of t/(d,e)
//   k_gram  : EXACT mean/std of mod_r from 16x16 Gram matrices
//   k_bmod  : fused rank-16 outer product + normalize + *baseT -> B2T bf16
//   k_gemm<128,128,true> : G1X = A2 . B2T^T   (512x1024x1024, bf16 out)
//   k_gemm<64,128,false> : out = CC + G1X . B5T^T (512x512x1024, fp32 out)
//
// GEMM staging (proven R2 structure): BOTH operands via global_load_lds
// width=16, lane-linear dst, XOR chunk swizzle (chunk c stores global chunk
// c^(r&7)) so fragment ds_read_b128 is ~2-way (free). R3's direct
// global->VGPR fragment loads regressed (~scattered 16-row gathers + vmcnt
// serialization) — do not reintroduce.

#define WS_STATS   1296
#define WS_MIS     4096        // [8][16][512][2] fp32
#define WS_MJS     135168
#define WS_BASET   266240      // [512][512][2] fp32
#define WS_A2      790528      // 512*1024 bf16
#define WS_B5T     1052672     // 512*1024 bf16
#define WS_G1X     1314816     // 8*512*1024 bf16
#define WS_B2T     3411968     // 8*1024*1024 bf16 ; end 7,606,272 floats (~30 MB)

typedef __attribute__((ext_vector_type(8))) short short8;
typedef __attribute__((ext_vector_type(4))) float f32x4;

__device__ __forceinline__ unsigned short f2bf(float f) {
    unsigned int u = __float_as_uint(f);
    u = (u + 0x7FFFu + ((u >> 16) & 1u)) >> 16;
    return (unsigned short)u;
}
__device__ __forceinline__ unsigned int pack2bf(float a, float b) {
    return (unsigned int)f2bf(a) | ((unsigned int)f2bf(b) << 16);
}
__device__ __forceinline__ void load_lds16(const unsigned short* g, unsigned short* l) {
    __builtin_amdgcn_global_load_lds((const __attribute__((address_space(1))) unsigned int*)g,
                                     (__attribute__((address_space(3))) unsigned int*)l, 16, 0, 0);
}

// ---------------------------------------------------------------------------
// k_trans: 32x32 tiled transposes. mode0: Wi->A2, mode1: Wj->B5T (*alpha,-im),
// mode2: base->baseT (fp32). alpha computed inline from rd (16 elems, L1-hot).
__global__ void k_trans(const float* __restrict__ Wi, const float* __restrict__ Wj,
                        const float* __restrict__ base, const float* __restrict__ rd,
                        float* __restrict__ ws) {
    __shared__ float2 tile[32][33];
    int mode = blockIdx.z;
    int bx = blockIdx.x, by = blockIdx.y;
    int tx = threadIdx.x & 31, ty = threadIdx.x >> 5;
    const float* src = (mode == 0) ? Wi : (mode == 1) ? Wj : base;
    for (int i = 0; i < 4; i++) {
        int rIn = by * 32 + ty + i * 8;
        int cIn = bx * 32 + tx;
        tile[ty + i * 8][tx] = *(const float2*)(src + ((size_t)rIn * 512 + cIn) * 2);
    }
    __syncthreads();
    if (mode == 0) {
        unsigned int* A2u = (unsigned int*)(ws + WS_A2);
        for (int i = 0; i < 4; i++) {
            int rOut = bx * 32 + ty + i * 8;
            int cOut = by * 32 + tx;
            float2 v = tile[tx][ty + i * 8];
            A2u[(size_t)rOut * 512 + cOut] = pack2bf(v.x, v.y);
        }
    } else if (mode == 1) {
        float ar = 0.f, ai = 0.f;
        for (int c = 0; c < 16; c++) { ar -= rd[2 * c]; ai -= rd[2 * c + 1]; }
        unsigned int* B5u = (unsigned int*)(ws + WS_B5T);
        for (int i = 0; i < 4; i++) {
            int rOut = bx * 32 + ty + i * 8;
            int cOut = by * 32 + tx;
            float2 v = tile[tx][ty + i * 8];
            float wr = ar * v.x - ai * v.y;
            float wi = ar * v.y + ai * v.x;
            B5u[(size_t)rOut * 512 + cOut] = pack2bf(wr, -wi);
        }
    } else {
        float* baseT = ws + WS_BASET;
        for (int i = 0; i < 4; i++) {
            int rOut = bx * 32 + ty + i * 8;
            int cOut = by * 32 + tx;
            *(float2*)(baseT + ((size_t)rOut * 512 + cOut) * 2) = tile[tx][ty + i * 8];
        }
    }
}

// ---------------------------------------------------------------------------
// k_mimj: blocks 0..255 -> mi_s; 256..511 -> mj_s. Each block serves one b;
// recomputes its t-rows (and d,e) in LDS — removes the k_prep launch.
__global__ void k_mimj(const float* __restrict__ x, const float* __restrict__ mt,
                       const float* __restrict__ inv, const float* __restrict__ mod_i,
                       const float* __restrict__ mod_j, float* __restrict__ ws) {
    __shared__ float tb[128];    // t[k][l], k<4, l<32 for this block's b
    __shared__ float deS[32];
    int blk = blockIdx.x;
    bool isMi = blk < 256;
    int id = (isMi ? blk : blk - 256) * 256 + threadIdx.x;
    int b = id >> 13, rm = id & 8191;
    int tid = threadIdx.x;
    if (tid < 128) {
        int k = tid >> 5, l = tid & 31;
        float s = 0.f;
        for (int c = 0; c < 16; c++) s += x[b * 16 + c] * mt[(k * 16 + c) * 32 + l];
        tb[tid] = s;
    }
    __syncthreads();
    if (tid < 16) {
        float i0 = inv[2 * tid], i1 = inv[2 * tid + 1];
        float z0 = tb[32 + 2 * tid], z1 = tb[32 + 2 * tid + 1];
        deS[2 * tid]     = i0 * z0 + i1 * z1;
        deS[2 * tid + 1] = i0 * z1 - i1 * z0;
    }
    __syncthreads();
    if (isMi) {
        float acc0 = 0.f, acc1 = 0.f;
        for (int c = 0; c < 16; c++) {
            const float* p = mod_i + (((size_t)c * 8192) + rm) * 2;
            float A0 = p[0] + tb[2 * c], A1 = p[1] + tb[2 * c + 1];
            float d = deS[2 * c], e = deS[2 * c + 1];
            acc0 += d * A0 - e * A1;
            acc1 += e * A0 + d * A1;
        }
        float* dst = ws + WS_MIS + ((size_t)b * 8192 + rm) * 2;
        dst[0] = acc0; dst[1] = acc1;
    } else {
        float acc0 = 0.f, acc1 = 0.f;
        for (int c = 0; c < 16; c++) {
            const float* p = mod_j + (((size_t)c * 8192) + rm) * 2;
            float A0 = p[0] + tb[64 + 2 * c], A1 = p[1] + tb[64 + 2 * c + 1];
            float z0 = tb[96 + 2 * c], z1 = tb[96 + 2 * c + 1];
            float w0 = -z0 * A0 + z1 * A1;
            float w1 =  z1 * A0 + z0 * A1;
            float i0 = inv[2 * c], i1 = inv[2 * c + 1];
            float den = w0 * w0 + w1 * w1;
            acc0 += (i0 * w0 + i1 * w1) / den;
            acc1 += (i0 * w1 - i1 * w0) / den;
        }
        float* dst = ws + WS_MJS + ((size_t)b * 8192 + rm) * 2;
        dst[0] = acc0; dst[1] = acc1;
    }
}

// ---------------------------------------------------------------------------
// k_gram: exact stats of mod_r via 16x16 Gram matrices (verified R3).
__global__ __launch_bounds__(256) void k_gram(float* __restrict__ ws) {
    __shared__ float2 Vs[16][130];
    __shared__ float2 Us[16][130];
    int b = blockIdx.x, tid = threadIdx.x;
    int r = tid >> 4, r2 = tid & 15;
    const float2* V = (const float2*)(ws + WS_MIS + (size_t)b * 16384);
    const float2* U = (const float2*)(ws + WS_MJS + (size_t)b * 16384);
    float Svr = 0, Svi = 0, Tvr = 0, Tvi = 0;
    float Sur = 0, Sui = 0, Tur = 0, Tui = 0;
    float ar = 0, ai = 0, br = 0, bi = 0;
    for (int h = 0; h < 4; h++) {
        for (int p = 0; p < 8; p++) {
            int f = tid + p * 256;
            int rr = f >> 7, mm = f & 127;
            Vs[rr][mm] = V[rr * 512 + h * 128 + mm];
            Us[rr][mm] = U[rr * 512 + h * 128 + mm];
        }
        __syncthreads();
        for (int mm = 0; mm < 128; mm++) {
            float2 v1 = Vs[r][mm], v2 = Vs[r2][mm];
            float2 u1 = Us[r][mm], u2 = Us[r2][mm];
            Svr += v1.x * v2.x - v1.y * v2.y;  Svi += v1.x * v2.y + v1.y * v2.x;
            Tvr += v1.x * v2.x + v1.y * v2.y;  Tvi += v1.y * v2.x - v1.x * v2.y;
            Sur += u1.x * u2.x - u1.y * u2.y;  Sui += u1.x * u2.y + u1.y * u2.x;
            Tur += u1.x * u2.x + u1.y * u2.y;  Tui += u1.y * u2.x - u1.x * u2.y;
            if (r2 == 0) { ar += v1.x; ai += v1.y; br += u1.x; bi += u1.y; }
        }
        __syncthreads();
    }
    float val = (Sur * Svr - Sui * Svi) + (Tur * Tvr - Tui * Tvi);
    float mterm = (r2 == 0) ? (br * ar - bi * ai) : 0.f;
    float* red = (float*)&Vs[0][0];
    red[tid] = val; red[256 + tid] = mterm;
    __syncthreads();
    for (int s = 128; s > 0; s >>= 1) {
        if (tid < s) { red[tid] += red[tid + s]; red[256 + tid] += red[256 + tid + s]; }
        __syncthreads();
    }
    if (tid == 0) {
        double MN = 262144.0;
        double mu = (double)red[256] / MN;
        double sumsq = 0.5 * (double)red[0];
        double var = (sumsq - MN * mu * mu) / (MN - 1.0);
        if (var < 1e-30) var = 1e-30;
        float* stats = ws + WS_STATS;
        stats[b * 2] = (float)mu;
        stats[b * 2 + 1] = (float)(1.0 / sqrt(var));
    }
}

// ---------------------------------------------------------------------------
// k_bmod: fused rank-16 outer product + normalization + base modulation,
// writes B2T bf16 expanded-transposed directly.
__global__ __launch_bounds__(256) void k_bmod(float* __restrict__ ws) {
    const float* mi_s  = ws + WS_MIS;
    const float* mj_s  = ws + WS_MJS;
    const float* baseT = ws + WS_BASET;
    const float* stats = ws + WS_STATS;
    unsigned int* B2T  = (unsigned int*)(ws + WS_B2T);
    int mt = blockIdx.x, nt = blockIdx.y, b = blockIdx.z;
    __shared__ float Ns[16][128];
    __shared__ float Ms[16][128];
    int tid = threadIdx.x, tx = tid & 15, ty = tid >> 4;
    const float* Nb = mj_s + (size_t)b * 16384;
    const float* Mb = mi_s + (size_t)b * 16384;
    int n0 = nt * 64, m0 = mt * 64;
    for (int i = 0; i < 4; i++) {
        int flat = tid + i * 256;
        int col = flat & 63, r = flat >> 6;
        float2 sa = *(const float2*)(Nb + ((size_t)r * 512 + n0 + col) * 2);
        Ns[r][col * 2] = sa.x; Ns[r][col * 2 + 1] = sa.y;
        float2 sb = *(const float2*)(Mb + ((size_t)r * 512 + m0 + col) * 2);
        Ms[r][col * 2] = sb.x; Ms[r][col * 2 + 1] = sb.y;
    }
    __syncthreads();
    float cr[4][4] = {}, ci[4][4] = {};
    for (int r = 0; r < 16; r++) {
        float nr[4], ni[4], mr[4], mi_[4];
        for (int i = 0; i < 4; i++) { nr[i] = Ns[r][(ty * 4 + i) * 2]; ni[i] = Ns[r][(ty * 4 + i) * 2 + 1]; }
        for (int j = 0; j < 4; j++) { mr[j] = Ms[r][(tx * 4 + j) * 2]; mi_[j] = Ms[r][(tx * 4 + j) * 2 + 1]; }
        for (int i = 0; i < 4; i++)
            for (int j = 0; j < 4; j++) {
                cr[i][j] += nr[i] * mr[j] - ni[i] * mi_[j];
                ci[i][j] += nr[i] * mi_[j] + ni[i] * mr[j];
            }
    }
    float mu = stats[b * 2], rstd = stats[b * 2 + 1];
    unsigned int* Bb = B2T + (size_t)b * 524288;
    for (int i = 0; i < 4; i++) {
        int n = n0 + ty * 4 + i;
        int mcol = m0 + tx * 4;
        const float4* bsp = (const float4*)(baseT + ((size_t)n * 512 + mcol) * 2);
        float4 b01 = bsp[0], b23 = bsp[1];
        float bsr[4] = {b01.x, b01.z, b23.x, b23.z};
        float bsi[4] = {b01.y, b01.w, b23.y, b23.w};
        uint4 w0, w1;
        unsigned int* p0 = (unsigned int*)&w0;
        unsigned int* p1 = (unsigned int*)&w1;
        for (int j = 0; j < 4; j++) {
            float wr = bsr[j] * (1.f + (cr[i][j] - mu) * rstd);
            float wi = bsi[j] * (1.f + ci[i][j]);
            p0[j] = pack2bf(wr, -wi);
            p1[j] = pack2bf(wi, wr);
        }
        *(uint4*)&Bb[(size_t)(2 * n) * 512 + mcol]     = w0;
        *(uint4*)&Bb[(size_t)(2 * n + 1) * 512 + mcol] = w1;
    }
}

// ---------------------------------------------------------------------------
// MFMA GEMM (R2's proven both-staged structure, tiled TM x TN):
// C[b][0..512 x ngl] tile (mBase,nBase); A[.. x 1024], BT[ngl x 1024].
// 4 waves as 2x2; wave-tile (TM/2)x(TN/2); XOR chunk swizzle on LDS.
template <int TM, int TN, bool OUT_BF16>
__global__ __launch_bounds__(256) void k_gemm(const unsigned short* __restrict__ Aall,
                                              const unsigned short* __restrict__ BTall,
                                              void* __restrict__ Call,
                                              const float* __restrict__ td,
                                              const float* __restrict__ rd,
                                              size_t a_bs, size_t bt_bs, size_t c_bs,
                                              int ngl) {
    constexpr int K = 1024;
    constexpr int IT = TM / 32, JT = TN / 32;
    constexpr int SMAB = (TM + TN) * 64;
    constexpr int SMC = OUT_BF16 ? TM * (TN + 8) : 0;
    constexpr int SMEMN = SMAB > SMC ? SMAB : SMC;
    __shared__ __align__(16) unsigned short smem[SMEMN];
    unsigned short* As = smem;
    unsigned short* Bs = smem + TM * 64;

    const int tid = threadIdx.x;
    const int b = blockIdx.z;
    const unsigned short* A  = Aall  + (size_t)b * a_bs;
    const unsigned short* BT = BTall + (size_t)b * bt_bs;
    const int mBase = blockIdx.y * TM;
    const int nBase = blockIdx.x * TN;
    const int wave = tid >> 6, lane = tid & 63;
    const int wm = wave >> 1, wn = wave & 1;
    const int l15 = lane & 15, q = lane >> 4;

    f32x4 acc[IT][JT];
    for (int i = 0; i < IT; i++)
        for (int j = 0; j < JT; j++) acc[i][j] = (f32x4)0.f;

    for (int k0 = 0; k0 < K; k0 += 64) {
#pragma unroll
        for (int p = 0; p < TM / 32; p++) {
            int flat = tid + p * 256;
            int r = flat >> 3, c = flat & 7;
            int gc = (c ^ (r & 7)) << 3;
            load_lds16(A + (size_t)(mBase + r) * K + k0 + gc, &As[flat << 3]);
        }
#pragma unroll
        for (int p = 0; p < TN / 32; p++) {
            int flat = tid + p * 256;
            int r = flat >> 3, c = flat & 7;
            int gc = (c ^ (r & 7)) << 3;
            load_lds16(BT + (size_t)(nBase + r) * K + k0 + gc, &Bs[flat << 3]);
        }
        __syncthreads();
#pragma unroll
        for (int ks = 0; ks < 2; ks++) {
            short8 af[IT], bfr[JT];
#pragma unroll
            for (int t = 0; t < IT; t++) {
                int ra = wm * (TM / 2) + t * 16 + l15;
                int ja = (ks * 4 + q) ^ (ra & 7);
                af[t] = *(const short8*)&As[ra * 64 + ja * 8];
            }
#pragma unroll
            for (int t = 0; t < JT; t++) {
                int rb = wn * (TN / 2) + t * 16 + l15;
                int jb = (ks * 4 + q) ^ (rb & 7);
                bfr[t] = *(const short8*)&Bs[rb * 64 + jb * 8];
            }
#pragma unroll
            for (int i = 0; i < IT; i++)
#pragma unroll
                for (int j = 0; j < JT; j++)
                    acc[i][j] = __builtin_amdgcn_mfma_f32_16x16x32_bf16(af[i], bfr[j], acc[i][j], 0, 0, 0);
        }
        __syncthreads();
    }

    if constexpr (OUT_BF16) {
        unsigned short* Cs = smem;
#pragma unroll
        for (int i = 0; i < IT; i++) {
            int row0 = wm * (TM / 2) + i * 16 + q * 4;
#pragma unroll
            for (int j = 0; j < JT; j++) {
                int col = wn * (TN / 2) + j * 16 + l15;
#pragma unroll
                for (int r = 0; r < 4; r++)
                    Cs[(row0 + r) * (TN + 8) + col] = f2bf(acc[i][j][r]);
            }
        }
        __syncthreads();
        unsigned short* C = (unsigned short*)Call + (size_t)b * c_bs;
#pragma unroll
        for (int p = 0; p < TM * TN / 2048; p++) {
            int flat = tid + p * 256;
            int r = flat / (TN / 8), c = flat % (TN / 8);
            short8 v = *(const short8*)&Cs[r * (TN + 8) + c * 8];
            *(short8*)(C + (size_t)(mBase + r) * ngl + nBase + c * 8) = v;
        }
    } else {
        float CC = 0.f;
        for (int c = 0; c < 16; c++) CC += td[2 * c + 1] * rd[2 * c + 1] - td[2 * c] * rd[2 * c];
        float* C = (float*)Call + (size_t)b * c_bs;
#pragma unroll
        for (int i = 0; i < IT; i++) {
            int row0 = mBase + wm * (TM / 2) + i * 16 + q * 4;
#pragma unroll
            for (int j = 0; j < JT; j++) {
                int col = nBase + wn * (TN / 2) + j * 16 + l15;
#pragma unroll
                for (int r = 0; r < 4; r++)
                    C[(size_t)(row0 + r) * ngl + col] = acc[i][j][r] + CC;
            }
        }
    }
}

// ---------------------------------------------------------------------------
extern "C" void kernel_launch(void* const* d_in, const int* in_sizes, int n_in,
                              void* d_out, int out_size, void* d_ws, size_t ws_size,
                              hipStream_t stream) {
    const float* x    = (const float*)d_in[0];
    const float* Wi   = (const float*)d_in[1];
    const float* Wj   = (const float*)d_in[2];
    const float* base = (const float*)d_in[3];
    const float* td   = (const float*)d_in[6];
    const float* rd   = (const float*)d_in[7];
    const float* modi = (const float*)d_in[8];
    const float* modj = (const float*)d_in[9];
    const float* inv  = (const float*)d_in[10];
    const float* mt   = (const float*)d_in[11];
    float* ws  = (float*)d_ws;
    float* out = (float*)d_out;

    unsigned short* A2  = (unsigned short*)(ws + WS_A2);
    unsigned short* B5T = (unsigned short*)(ws + WS_B5T);
    unsigned short* B2T = (unsigned short*)(ws + WS_B2T);
    unsigned short* G1X = (unsigned short*)(ws + WS_G1X);

    k_trans<<<dim3(16, 16, 3), 256, 0, stream>>>(Wi, Wj, base, rd, ws);
    k_mimj<<<512, 256, 0, stream>>>(x, mt, inv, modi, modj, ws);
    k_gram<<<8, 256, 0, stream>>>(ws);
    k_bmod<<<dim3(8, 8, 8), 256, 0, stream>>>(ws);
    k_gemm<128, 128, true><<<dim3(8, 4, 8), 256, 0, stream>>>(
        A2, B2T, (void*)G1X, td, rd, (size_t)0, (size_t)1048576, (size_t)524288, 1024);
    k_gemm<64, 128, false><<<dim3(4, 8, 8), 256, 0, stream>>>(
        G1X, B5T, (void*)out, td, rd, (size_t)524288, (size_t)0, (size_t)262144, 512);
}

// Round 5
// 150.870 us; speedup vs baseline: 1.1859x; 1.1423x over previous
//
#include <hip/hip_runtime.h>
#include <hip/hip_bf16.h>
#include <math.h>

// Shapes (fixed): B=8, C=16, R=16, M=N=512. K of both real GEMMs = 1024.
//
// Pipeline (7 launches):
//   k_trans : Wi->A2 bf16 [m1][2m+c]; Wj->B5T bf16 [n1][2n+c] (*alpha, -im);
//             base->baseT fp32 [n][m]
//   k_mimj  : rank-16 factors mi_s/mj_s (fp32), inline per-block prep
//   k_gram1 : partial 16x16 Gram matrices per (b, 64-col chunk)  [64 blocks]
//   k_gram2 : finish Grams -> exact mean/std (ddof=1)            [8 blocks]
//   k_bmod  : fused rank-16 outer product + normalize + *baseT -> B2T bf16
//   k_gemm<128,128,true>  : G1X = A2 . B2T^T   (512x1024x1024, bf16 out)
//   k_gemm<128,128,false> : out = CC + G1X . B5T^T (512x512x1024, fp32 out)
//
// GEMM staging (proven R2 structure): BOTH operands via global_load_lds
// width=16, lane-linear dst, XOR chunk swizzle; 128x128 tiles for BOTH gemms
// (R4's 64x128 gemmB = 1.5x staging bytes/MFMA -> regressed; reverted).

#define WS_STATS   1296
#define WS_MIS     4096        // [8][16][512][2] fp32
#define WS_MJS     135168
#define WS_BASET   266240      // [512][512][2] fp32
#define WS_A2      790528      // 512*1024 bf16
#define WS_B5T     1052672     // 512*1024 bf16
#define WS_G1X     1314816     // 8*512*1024 bf16
#define WS_B2T     3411968     // 8*1024rows*512 uint(packed bf16 pair)
#define WS_GP      7606272     // gram partials [8][8][256][8] fp32
#define WS_CS      7737344     // colsum partials [8][8][16][4] fp32 ; end 7741440

typedef __attribute__((ext_vector_type(8))) short short8;
typedef __attribute__((ext_vector_type(4))) float f32x4;

__device__ __forceinline__ unsigned short f2bf(float f) {
    unsigned int u = __float_as_uint(f);
    u = (u + 0x7FFFu + ((u >> 16) & 1u)) >> 16;
    return (unsigned short)u;
}
__device__ __forceinline__ unsigned int pack2bf(float a, float b) {
    return (unsigned int)f2bf(a) | ((unsigned int)f2bf(b) << 16);
}
__device__ __forceinline__ void load_lds16(const unsigned short* g, unsigned short* l) {
    __builtin_amdgcn_global_load_lds((const __attribute__((address_space(1))) unsigned int*)g,
                                     (__attribute__((address_space(3))) unsigned int*)l, 16, 0, 0);
}

// ---------------------------------------------------------------------------
__global__ void k_trans(const float* __restrict__ Wi, const float* __restrict__ Wj,
                        const float* __restrict__ base, const float* __restrict__ rd,
                        float* __restrict__ ws) {
    __shared__ float2 tile[32][33];
    int mode = blockIdx.z;
    int bx = blockIdx.x, by = blockIdx.y;
    int tx = threadIdx.x & 31, ty = threadIdx.x >> 5;
    const float* src = (mode == 0) ? Wi : (mode == 1) ? Wj : base;
    for (int i = 0; i < 4; i++) {
        int rIn = by * 32 + ty + i * 8;
        int cIn = bx * 32 + tx;
        tile[ty + i * 8][tx] = *(const float2*)(src + ((size_t)rIn * 512 + cIn) * 2);
    }
    __syncthreads();
    if (mode == 0) {
        unsigned int* A2u = (unsigned int*)(ws + WS_A2);
        for (int i = 0; i < 4; i++) {
            int rOut = bx * 32 + ty + i * 8;
            int cOut = by * 32 + tx;
            float2 v = tile[tx][ty + i * 8];
            A2u[(size_t)rOut * 512 + cOut] = pack2bf(v.x, v.y);
        }
    } else if (mode == 1) {
        float ar = 0.f, ai = 0.f;
        for (int c = 0; c < 16; c++) { ar -= rd[2 * c]; ai -= rd[2 * c + 1]; }
        unsigned int* B5u = (unsigned int*)(ws + WS_B5T);
        for (int i = 0; i < 4; i++) {
            int rOut = bx * 32 + ty + i * 8;
            int cOut = by * 32 + tx;
            float2 v = tile[tx][ty + i * 8];
            float wr = ar * v.x - ai * v.y;
            float wi = ar * v.y + ai * v.x;
            B5u[(size_t)rOut * 512 + cOut] = pack2bf(wr, -wi);
        }
    } else {
        float* baseT = ws + WS_BASET;
        for (int i = 0; i < 4; i++) {
            int rOut = bx * 32 + ty + i * 8;
            int cOut = by * 32 + tx;
            *(float2*)(baseT + ((size_t)rOut * 512 + cOut) * 2) = tile[tx][ty + i * 8];
        }
    }
}

// ---------------------------------------------------------------------------
__global__ void k_mimj(const float* __restrict__ x, const float* __restrict__ mt,
                       const float* __restrict__ inv, const float* __restrict__ mod_i,
                       const float* __restrict__ mod_j, float* __restrict__ ws) {
    __shared__ float tb[128];
    __shared__ float deS[32];
    int blk = blockIdx.x;
    bool isMi = blk < 256;
    int id = (isMi ? blk : blk - 256) * 256 + threadIdx.x;
    int b = id >> 13, rm = id & 8191;
    int tid = threadIdx.x;
    if (tid < 128) {
        int k = tid >> 5, l = tid & 31;
        float s = 0.f;
        for (int c = 0; c < 16; c++) s += x[b * 16 + c] * mt[(k * 16 + c) * 32 + l];
        tb[tid] = s;
    }
    __syncthreads();
    if (tid < 16) {
        float i0 = inv[2 * tid], i1 = inv[2 * tid + 1];
        float z0 = tb[32 + 2 * tid], z1 = tb[32 + 2 * tid + 1];
        deS[2 * tid]     = i0 * z0 + i1 * z1;
        deS[2 * tid + 1] = i0 * z1 - i1 * z0;
    }
    __syncthreads();
    if (isMi) {
        float acc0 = 0.f, acc1 = 0.f;
        for (int c = 0; c < 16; c++) {
            const float* p = mod_i + (((size_t)c * 8192) + rm) * 2;
            float A0 = p[0] + tb[2 * c], A1 = p[1] + tb[2 * c + 1];
            float d = deS[2 * c], e = deS[2 * c + 1];
            acc0 += d * A0 - e * A1;
            acc1 += e * A0 + d * A1;
        }
        float* dst = ws + WS_MIS + ((size_t)b * 8192 + rm) * 2;
        dst[0] = acc0; dst[1] = acc1;
    } else {
        float acc0 = 0.f, acc1 = 0.f;
        for (int c = 0; c < 16; c++) {
            const float* p = mod_j + (((size_t)c * 8192) + rm) * 2;
            float A0 = p[0] + tb[64 + 2 * c], A1 = p[1] + tb[64 + 2 * c + 1];
            float z0 = tb[96 + 2 * c], z1 = tb[96 + 2 * c + 1];
            float w0 = -z0 * A0 + z1 * A1;
            float w1 =  z1 * A0 + z0 * A1;
            float i0 = inv[2 * c], i1 = inv[2 * c + 1];
            float den = w0 * w0 + w1 * w1;
            acc0 += (i0 * w0 + i1 * w1) / den;
            acc1 += (i0 * w1 - i1 * w0) / den;
        }
        float* dst = ws + WS_MJS + ((size_t)b * 8192 + rm) * 2;
        dst[0] = acc0; dst[1] = acc1;
    }
}

// ---------------------------------------------------------------------------
// k_gram1: partial Grams over a 64-column chunk. grid (chunk=8, b=8).
// Thread tid = (r,r2) pair; accumulates S=plain, T=conj grams for V(mi), U(mj)
// plus column-sum partials (r2==0 lanes).
__global__ __launch_bounds__(256) void k_gram1(float* __restrict__ ws) {
    __shared__ float2 Vs[16][66];   // pad 66: r2-strided reads -> 2-way (free)
    __shared__ float2 Us[16][66];
    int ch = blockIdx.x, b = blockIdx.y, tid = threadIdx.x;
    int r = tid >> 4, r2 = tid & 15;
    const float2* V = (const float2*)(ws + WS_MIS + (size_t)b * 16384);
    const float2* U = (const float2*)(ws + WS_MJS + (size_t)b * 16384);
    int c0 = ch * 64;
    for (int p = 0; p < 4; p++) {
        int f = tid + p * 256;
        int rr = f >> 6, mm = f & 63;
        Vs[rr][mm] = V[rr * 512 + c0 + mm];
        Us[rr][mm] = U[rr * 512 + c0 + mm];
    }
    __syncthreads();
    float Svr = 0, Svi = 0, Tvr = 0, Tvi = 0;
    float Sur = 0, Sui = 0, Tur = 0, Tui = 0;
    float ar = 0, ai = 0, br = 0, bi = 0;
    for (int mm = 0; mm < 64; mm++) {
        float2 v1 = Vs[r][mm], v2 = Vs[r2][mm];
        float2 u1 = Us[r][mm], u2 = Us[r2][mm];
        Svr += v1.x * v2.x - v1.y * v2.y;  Svi += v1.x * v2.y + v1.y * v2.x;
        Tvr += v1.x * v2.x + v1.y * v2.y;  Tvi += v1.y * v2.x - v1.x * v2.y;
        Sur += u1.x * u2.x - u1.y * u2.y;  Sui += u1.x * u2.y + u1.y * u2.x;
        Tur += u1.x * u2.x + u1.y * u2.y;  Tui += u1.y * u2.x - u1.x * u2.y;
        if (r2 == 0) { ar += v1.x; ai += v1.y; br += u1.x; bi += u1.y; }
    }
    float4* g4 = (float4*)(ws + WS_GP + (((size_t)b * 8 + ch) * 256 + tid) * 8);
    g4[0] = make_float4(Svr, Svi, Tvr, Tvi);
    g4[1] = make_float4(Sur, Sui, Tur, Tui);
    if (r2 == 0)
        *(float4*)(ws + WS_CS + (((size_t)b * 8 + ch) * 16 + r) * 4) =
            make_float4(ar, ai, br, bi);
}

// ---------------------------------------------------------------------------
// k_gram2: finish Gram sums across chunks, multiply, reduce -> mu, 1/std.
//   sumsq = 0.5 * sum_{r,r2} [Re(Su.Sv) + Re(Tu.Tv)] ; sum = Re(sum_r b_r a_r)
__global__ __launch_bounds__(256) void k_gram2(float* __restrict__ ws) {
    __shared__ float red[256];
    __shared__ float red2[16];
    int b = blockIdx.x, tid = threadIdx.x;
    float Svr = 0, Svi = 0, Tvr = 0, Tvi = 0;
    float Sur = 0, Sui = 0, Tur = 0, Tui = 0;
    for (int ch = 0; ch < 8; ch++) {
        const float4* g4 = (const float4*)(ws + WS_GP + (((size_t)b * 8 + ch) * 256 + tid) * 8);
        float4 a0 = g4[0], a1 = g4[1];
        Svr += a0.x; Svi += a0.y; Tvr += a0.z; Tvi += a0.w;
        Sur += a1.x; Sui += a1.y; Tur += a1.z; Tui += a1.w;
    }
    red[tid] = (Sur * Svr - Sui * Svi) + (Tur * Tvr - Tui * Tvi);
    if (tid < 16) {
        float ar = 0, ai = 0, br = 0, bi = 0;
        for (int ch = 0; ch < 8; ch++) {
            float4 c = *(const float4*)(ws + WS_CS + (((size_t)b * 8 + ch) * 16 + tid) * 4);
            ar += c.x; ai += c.y; br += c.z; bi += c.w;
        }
        red2[tid] = br * ar - bi * ai;
    }
    __syncthreads();
    for (int s = 128; s > 0; s >>= 1) {
        if (tid < s) red[tid] += red[tid + s];
        __syncthreads();
    }
    if (tid == 0) {
        float msum = 0.f;
        for (int i = 0; i < 16; i++) msum += red2[i];
        double MN = 262144.0;
        double mu = (double)msum / MN;
        double sumsq = 0.5 * (double)red[0];
        double var = (sumsq - MN * mu * mu) / (MN - 1.0);
        if (var < 1e-30) var = 1e-30;
        float* stats = ws + WS_STATS;
        stats[b * 2] = (float)mu;
        stats[b * 2 + 1] = (float)(1.0 / sqrt(var));
    }
}

// ---------------------------------------------------------------------------
// k_bmod: fused rank-16 outer product + normalization + base modulation.
// Thread map: m = m0 + tx + j*16 (lane-contiguous) -> coalesced baseT reads
// and B2T stores (wd0-style).
__global__ __launch_bounds__(256) void k_bmod(float* __restrict__ ws) {
    const float* mi_s  = ws + WS_MIS;
    const float* mj_s  = ws + WS_MJS;
    const float* baseT = ws + WS_BASET;
    const float* stats = ws + WS_STATS;
    unsigned int* B2T  = (unsigned int*)(ws + WS_B2T);
    int mt = blockIdx.x, nt = blockIdx.y, b = blockIdx.z;
    __shared__ float Ns[16][128];
    __shared__ float Ms[16][128];
    int tid = threadIdx.x, tx = tid & 15, ty = tid >> 4;
    const float* Nb = mj_s + (size_t)b * 16384;
    const float* Mb = mi_s + (size_t)b * 16384;
    int n0 = nt * 64, m0 = mt * 64;
    for (int i = 0; i < 4; i++) {
        int flat = tid + i * 256;
        int col = flat & 63, r = flat >> 6;
        float2 sa = *(const float2*)(Nb + ((size_t)r * 512 + n0 + col) * 2);
        Ns[r][col * 2] = sa.x; Ns[r][col * 2 + 1] = sa.y;
        float2 sb = *(const float2*)(Mb + ((size_t)r * 512 + m0 + col) * 2);
        Ms[r][col * 2] = sb.x; Ms[r][col * 2 + 1] = sb.y;
    }
    __syncthreads();
    float cr[4][4] = {}, ci[4][4] = {};
    for (int r = 0; r < 16; r++) {
        float nr[4], ni[4], mr[4], mi_[4];
        for (int i = 0; i < 4; i++) { nr[i] = Ns[r][(ty * 4 + i) * 2]; ni[i] = Ns[r][(ty * 4 + i) * 2 + 1]; }
        for (int j = 0; j < 4; j++) { mr[j] = Ms[r][(tx + j * 16) * 2]; mi_[j] = Ms[r][(tx + j * 16) * 2 + 1]; }
        for (int i = 0; i < 4; i++)
            for (int j = 0; j < 4; j++) {
                cr[i][j] += nr[i] * mr[j] - ni[i] * mi_[j];
                ci[i][j] += nr[i] * mi_[j] + ni[i] * mr[j];
            }
    }
    float mu = stats[b * 2], rstd = stats[b * 2 + 1];
    unsigned int* Bb = B2T + (size_t)b * 524288;
    for (int i = 0; i < 4; i++) {
        int n = n0 + ty * 4 + i;
        for (int j = 0; j < 4; j++) {
            int m = m0 + tx + j * 16;
            float2 bs = *(const float2*)(baseT + ((size_t)n * 512 + m) * 2);
            float wr = bs.x * (1.f + (cr[i][j] - mu) * rstd);
            float wi = bs.y * (1.f + ci[i][j]);
            Bb[(size_t)(2 * n) * 512 + m]     = pack2bf(wr, -wi);
            Bb[(size_t)(2 * n + 1) * 512 + m] = pack2bf(wi, wr);
        }
    }
}

// ---------------------------------------------------------------------------
// MFMA GEMM (R2-proven both-staged structure, tiled TM x TN):
template <int TM, int TN, bool OUT_BF16>
__global__ __launch_bounds__(256) void k_gemm(const unsigned short* __restrict__ Aall,
                                              const unsigned short* __restrict__ BTall,
                                              void* __restrict__ Call,
                                              const float* __restrict__ td,
                                              const float* __restrict__ rd,
                                              size_t a_bs, size_t bt_bs, size_t c_bs,
                                              int ngl) {
    constexpr int K = 1024;
    constexpr int IT = TM / 32, JT = TN / 32;
    constexpr int SMAB = (TM + TN) * 64;
    constexpr int SMC = OUT_BF16 ? TM * (TN + 8) : 0;
    constexpr int SMEMN = SMAB > SMC ? SMAB : SMC;
    __shared__ __align__(16) unsigned short smem[SMEMN];
    unsigned short* As = smem;
    unsigned short* Bs = smem + TM * 64;

    const int tid = threadIdx.x;
    const int b = blockIdx.z;
    const unsigned short* A  = Aall  + (size_t)b * a_bs;
    const unsigned short* BT = BTall + (size_t)b * bt_bs;
    const int mBase = blockIdx.y * TM;
    const int nBase = blockIdx.x * TN;
    const int wave = tid >> 6, lane = tid & 63;
    const int wm = wave >> 1, wn = wave & 1;
    const int l15 = lane & 15, q = lane >> 4;

    f32x4 acc[IT][JT];
    for (int i = 0; i < IT; i++)
        for (int j = 0; j < JT; j++) acc[i][j] = (f32x4)0.f;

    for (int k0 = 0; k0 < K; k0 += 64) {
#pragma unroll
        for (int p = 0; p < TM / 32; p++) {
            int flat = tid + p * 256;
            int r = flat >> 3, c = flat & 7;
            int gc = (c ^ (r & 7)) << 3;
            load_lds16(A + (size_t)(mBase + r) * K + k0 + gc, &As[flat << 3]);
        }
#pragma unroll
        for (int p = 0; p < TN / 32; p++) {
            int flat = tid + p * 256;
            int r = flat >> 3, c = flat & 7;
            int gc = (c ^ (r & 7)) << 3;
            load_lds16(BT + (size_t)(nBase + r) * K + k0 + gc, &Bs[flat << 3]);
        }
        __syncthreads();
#pragma unroll
        for (int ks = 0; ks < 2; ks++) {
            short8 af[IT], bfr[JT];
#pragma unroll
            for (int t = 0; t < IT; t++) {
                int ra = wm * (TM / 2) + t * 16 + l15;
                int ja = (ks * 4 + q) ^ (ra & 7);
                af[t] = *(const short8*)&As[ra * 64 + ja * 8];
            }
#pragma unroll
            for (int t = 0; t < JT; t++) {
                int rb = wn * (TN / 2) + t * 16 + l15;
                int jb = (ks * 4 + q) ^ (rb & 7);
                bfr[t] = *(const short8*)&Bs[rb * 64 + jb * 8];
            }
#pragma unroll
            for (int i = 0; i < IT; i++)
#pragma unroll
                for (int j = 0; j < JT; j++)
                    acc[i][j] = __builtin_amdgcn_mfma_f32_16x16x32_bf16(af[i], bfr[j], acc[i][j], 0, 0, 0);
        }
        __syncthreads();
    }

    if constexpr (OUT_BF16) {
        unsigned short* Cs = smem;
#pragma unroll
        for (int i = 0; i < IT; i++) {
            int row0 = wm * (TM / 2) + i * 16 + q * 4;
#pragma unroll
            for (int j = 0; j < JT; j++) {
                int col = wn * (TN / 2) + j * 16 + l15;
#pragma unroll
                for (int r = 0; r < 4; r++)
                    Cs[(row0 + r) * (TN + 8) + col] = f2bf(acc[i][j][r]);
            }
        }
        __syncthreads();
        unsigned short* C = (unsigned short*)Call + (size_t)b * c_bs;
#pragma unroll
        for (int p = 0; p < TM * TN / 2048; p++) {
            int flat = tid + p * 256;
            int r = flat / (TN / 8), c = flat % (TN / 8);
            short8 v = *(const short8*)&Cs[r * (TN + 8) + c * 8];
            *(short8*)(C + (size_t)(mBase + r) * ngl + nBase + c * 8) = v;
        }
    } else {
        float CC = 0.f;
        for (int c = 0; c < 16; c++) CC += td[2 * c + 1] * rd[2 * c + 1] - td[2 * c] * rd[2 * c];
        float* C = (float*)Call + (size_t)b * c_bs;
#pragma unroll
        for (int i = 0; i < IT; i++) {
            int row0 = mBase + wm * (TM / 2) + i * 16 + q * 4;
#pragma unroll
            for (int j = 0; j < JT; j++) {
                int col = nBase + wn * (TN / 2) + j * 16 + l15;
#pragma unroll
                for (int r = 0; r < 4; r++)
                    C[(size_t)(row0 + r) * ngl + col] = acc[i][j][r] + CC;
            }
        }
    }
}

// ---------------------------------------------------------------------------
extern "C" void kernel_launch(void* const* d_in, const int* in_sizes, int n_in,
                              void* d_out, int out_size, void* d_ws, size_t ws_size,
                              hipStream_t stream) {
    const float* x    = (const float*)d_in[0];
    const float* Wi   = (const float*)d_in[1];
    const float* Wj   = (const float*)d_in[2];
    const float* base = (const float*)d_in[3];
    const float* td   = (const float*)d_in[6];
    const float* rd   = (const float*)d_in[7];
    const float* modi = (const float*)d_in[8];
    const float* modj = (const float*)d_in[9];
    const float* inv  = (const float*)d_in[10];
    const float* mt   = (const float*)d_in[11];
    float* ws  = (float*)d_ws;
    float* out = (float*)d_out;

    unsigned short* A2  = (unsigned short*)(ws + WS_A2);
    unsigned short* B5T = (unsigned short*)(ws + WS_B5T);
    unsigned short* B2T = (unsigned short*)(ws + WS_B2T);
    unsigned short* G1X = (unsigned short*)(ws + WS_G1X);

    k_trans<<<dim3(16, 16, 3), 256, 0, stream>>>(Wi, Wj, base, rd, ws);
    k_mimj<<<512, 256, 0, stream>>>(x, mt, inv, modi, modj, ws);
    k_gram1<<<dim3(8, 8), 256, 0, stream>>>(ws);
    k_gram2<<<8, 256, 0, stream>>>(ws);
    k_bmod<<<dim3(8, 8, 8), 256, 0, stream>>>(ws);
    k_gemm<128, 128, true><<<dim3(8, 4, 8), 256, 0, stream>>>(
        A2, B2T, (void*)G1X, td, rd, (size_t)0, (size_t)1048576, (size_t)524288, 1024);
    k_gemm<128, 128, false><<<dim3(4, 4, 8), 256, 0, stream>>>(
        G1X, B5T, (void*)out, td, rd, (size_t)524288, (size_t)0, (size_t)262144, 512);
}

// Round 6
// 136.599 us; speedup vs baseline: 1.3097x; 1.1045x over previous
//
#include <hip/hip_runtime.h>
#include <hip/hip_bf16.h>
#include <math.h>

// Shapes (fixed): B=8, C=16, R=16, M=N=512. K of both real GEMMs = 1024.
//
// Pipeline (6 launches):
//   k_front : [blk 0..767] 32x32 transposes: Wi->A2 bf16, Wj->B5T bf16
//             (*alpha,-im), base->baseT fp32; [blk 768..1279] rank-16
//             factors mi_s/mj_s (fp32) with inline per-block t/(d,e) prep
//   k_gram1 : partial 16x16 Gram matrices per (b, 64-col chunk)  [64 blocks]
//   k_gram2 : finish Grams -> exact mean/std (ddof=1)            [8 blocks]
//   k_bmod  : fused rank-16 outer product + normalize + *baseT -> B2T bf16
//   k_gemm<128,128,true>  : G1X = A2 . B2T^T   (512x1024x1024, bf16 out)
//   k_gemm<64,128,false>  : out = CC + G1X . B5T^T (512x512x1024, fp32 out)
//
// GEMM: both operands staged via global_load_lds width=16, lane-linear dst,
// XOR chunk swizzle (frag ds_read_b128 ~2-way = free). R6: DOUBLE-BUFFERED
// single-barrier K-loop — barrier's implicit vmcnt(0) drain now overlaps a
// full compute phase (at 1 block/CU there is no inter-block overlap to hide
// it otherwise). gemmB at TM=64 -> 256 blocks = full GPU.

#define WS_STATS   1296
#define WS_MIS     4096        // [8][16][512][2] fp32
#define WS_MJS     135168
#define WS_BASET   266240      // [512][512][2] fp32
#define WS_A2      790528      // 512*1024 bf16
#define WS_B5T     1052672     // 512*1024 bf16
#define WS_G1X     1314816     // 8*512*1024 bf16
#define WS_B2T     3411968     // 8*[1024][512] uint (packed bf16 pair)
#define WS_GP      7606272     // gram partials [8][8][256][8] fp32
#define WS_CS      7737344     // colsum partials [8][8][16][4] fp32 ; end 7741440

typedef __attribute__((ext_vector_type(8))) short short8;
typedef __attribute__((ext_vector_type(4))) float f32x4;

__device__ __forceinline__ unsigned short f2bf(float f) {
    unsigned int u = __float_as_uint(f);
    u = (u + 0x7FFFu + ((u >> 16) & 1u)) >> 16;
    return (unsigned short)u;
}
__device__ __forceinline__ unsigned int pack2bf(float a, float b) {
    return (unsigned int)f2bf(a) | ((unsigned int)f2bf(b) << 16);
}
__device__ __forceinline__ void load_lds16(const unsigned short* g, unsigned short* l) {
    __builtin_amdgcn_global_load_lds((const __attribute__((address_space(1))) unsigned int*)g,
                                     (__attribute__((address_space(3))) unsigned int*)l, 16, 0, 0);
}

// ---------------------------------------------------------------------------
// k_front: blocks 0..767 = transposes (mode=blk>>8); blocks 768..1279 = mimj.
__global__ void k_front(const float* __restrict__ Wi, const float* __restrict__ Wj,
                        const float* __restrict__ base, const float* __restrict__ rd,
                        const float* __restrict__ x, const float* __restrict__ mt,
                        const float* __restrict__ inv, const float* __restrict__ mod_i,
                        const float* __restrict__ mod_j, float* __restrict__ ws) {
    __shared__ __align__(16) char shmem[32 * 33 * 8];
    int blk = blockIdx.x;
    int tid = threadIdx.x;
    if (blk < 768) {
        float2(*tile)[33] = (float2(*)[33])shmem;
        int mode = blk >> 8;
        int idx = blk & 255;
        int bx = idx & 15, by = idx >> 4;
        int tx = tid & 31, ty = tid >> 5;
        const float* src = (mode == 0) ? Wi : (mode == 1) ? Wj : base;
        for (int i = 0; i < 4; i++) {
            int rIn = by * 32 + ty + i * 8;
            int cIn = bx * 32 + tx;
            tile[ty + i * 8][tx] = *(const float2*)(src + ((size_t)rIn * 512 + cIn) * 2);
        }
        __syncthreads();
        if (mode == 0) {
            unsigned int* A2u = (unsigned int*)(ws + WS_A2);
            for (int i = 0; i < 4; i++) {
                int rOut = bx * 32 + ty + i * 8;
                int cOut = by * 32 + tx;
                float2 v = tile[tx][ty + i * 8];
                A2u[(size_t)rOut * 512 + cOut] = pack2bf(v.x, v.y);
            }
        } else if (mode == 1) {
            float ar = 0.f, ai = 0.f;
            for (int c = 0; c < 16; c++) { ar -= rd[2 * c]; ai -= rd[2 * c + 1]; }
            unsigned int* B5u = (unsigned int*)(ws + WS_B5T);
            for (int i = 0; i < 4; i++) {
                int rOut = bx * 32 + ty + i * 8;
                int cOut = by * 32 + tx;
                float2 v = tile[tx][ty + i * 8];
                float wr = ar * v.x - ai * v.y;
                float wi = ar * v.y + ai * v.x;
                B5u[(size_t)rOut * 512 + cOut] = pack2bf(wr, -wi);
            }
        } else {
            float* baseT = ws + WS_BASET;
            for (int i = 0; i < 4; i++) {
                int rOut = bx * 32 + ty + i * 8;
                int cOut = by * 32 + tx;
                *(float2*)(baseT + ((size_t)rOut * 512 + cOut) * 2) = tile[tx][ty + i * 8];
            }
        }
    } else {
        float* tb = (float*)shmem;          // 128 floats
        float* deS = (float*)shmem + 128;   // 32 floats
        int blk2 = blk - 768;
        bool isMi = blk2 < 256;
        int id = (isMi ? blk2 : blk2 - 256) * 256 + tid;
        int b = id >> 13, rm = id & 8191;
        if (tid < 128) {
            int k = tid >> 5, l = tid & 31;
            float s = 0.f;
            for (int c = 0; c < 16; c++) s += x[b * 16 + c] * mt[(k * 16 + c) * 32 + l];
            tb[tid] = s;
        }
        __syncthreads();
        if (tid < 16) {
            float i0 = inv[2 * tid], i1 = inv[2 * tid + 1];
            float z0 = tb[32 + 2 * tid], z1 = tb[32 + 2 * tid + 1];
            deS[2 * tid]     = i0 * z0 + i1 * z1;
            deS[2 * tid + 1] = i0 * z1 - i1 * z0;
        }
        __syncthreads();
        if (isMi) {
            float acc0 = 0.f, acc1 = 0.f;
            for (int c = 0; c < 16; c++) {
                const float* p = mod_i + (((size_t)c * 8192) + rm) * 2;
                float A0 = p[0] + tb[2 * c], A1 = p[1] + tb[2 * c + 1];
                float d = deS[2 * c], e = deS[2 * c + 1];
                acc0 += d * A0 - e * A1;
                acc1 += e * A0 + d * A1;
            }
            float* dst = ws + WS_MIS + ((size_t)b * 8192 + rm) * 2;
            dst[0] = acc0; dst[1] = acc1;
        } else {
            float acc0 = 0.f, acc1 = 0.f;
            for (int c = 0; c < 16; c++) {
                const float* p = mod_j + (((size_t)c * 8192) + rm) * 2;
                float A0 = p[0] + tb[64 + 2 * c], A1 = p[1] + tb[64 + 2 * c + 1];
                float z0 = tb[96 + 2 * c], z1 = tb[96 + 2 * c + 1];
                float w0 = -z0 * A0 + z1 * A1;
                float w1 =  z1 * A0 + z0 * A1;
                float i0 = inv[2 * c], i1 = inv[2 * c + 1];
                float den = w0 * w0 + w1 * w1;
                acc0 += (i0 * w0 + i1 * w1) / den;
                acc1 += (i0 * w1 - i1 * w0) / den;
            }
            float* dst = ws + WS_MJS + ((size_t)b * 8192 + rm) * 2;
            dst[0] = acc0; dst[1] = acc1;
        }
    }
}

// ---------------------------------------------------------------------------
// k_gram1: partial Grams over a 64-column chunk. grid (chunk=8, b=8).
__global__ __launch_bounds__(256) void k_gram1(float* __restrict__ ws) {
    __shared__ float2 Vs[16][66];
    __shared__ float2 Us[16][66];
    int ch = blockIdx.x, b = blockIdx.y, tid = threadIdx.x;
    int r = tid >> 4, r2 = tid & 15;
    const float2* V = (const float2*)(ws + WS_MIS + (size_t)b * 16384);
    const float2* U = (const float2*)(ws + WS_MJS + (size_t)b * 16384);
    int c0 = ch * 64;
    for (int p = 0; p < 4; p++) {
        int f = tid + p * 256;
        int rr = f >> 6, mm = f & 63;
        Vs[rr][mm] = V[rr * 512 + c0 + mm];
        Us[rr][mm] = U[rr * 512 + c0 + mm];
    }
    __syncthreads();
    float Svr = 0, Svi = 0, Tvr = 0, Tvi = 0;
    float Sur = 0, Sui = 0, Tur = 0, Tui = 0;
    float ar = 0, ai = 0, br = 0, bi = 0;
    for (int mm = 0; mm < 64; mm++) {
        float2 v1 = Vs[r][mm], v2 = Vs[r2][mm];
        float2 u1 = Us[r][mm], u2 = Us[r2][mm];
        Svr += v1.x * v2.x - v1.y * v2.y;  Svi += v1.x * v2.y + v1.y * v2.x;
        Tvr += v1.x * v2.x + v1.y * v2.y;  Tvi += v1.y * v2.x - v1.x * v2.y;
        Sur += u1.x * u2.x - u1.y * u2.y;  Sui += u1.x * u2.y + u1.y * u2.x;
        Tur += u1.x * u2.x + u1.y * u2.y;  Tui += u1.y * u2.x - u1.x * u2.y;
        if (r2 == 0) { ar += v1.x; ai += v1.y; br += u1.x; bi += u1.y; }
    }
    float4* g4 = (float4*)(ws + WS_GP + (((size_t)b * 8 + ch) * 256 + tid) * 8);
    g4[0] = make_float4(Svr, Svi, Tvr, Tvi);
    g4[1] = make_float4(Sur, Sui, Tur, Tui);
    if (r2 == 0)
        *(float4*)(ws + WS_CS + (((size_t)b * 8 + ch) * 16 + r) * 4) =
            make_float4(ar, ai, br, bi);
}

// ---------------------------------------------------------------------------
__global__ __launch_bounds__(256) void k_gram2(float* __restrict__ ws) {
    __shared__ float red[256];
    __shared__ float red2[16];
    int b = blockIdx.x, tid = threadIdx.x;
    float Svr = 0, Svi = 0, Tvr = 0, Tvi = 0;
    float Sur = 0, Sui = 0, Tur = 0, Tui = 0;
    for (int ch = 0; ch < 8; ch++) {
        const float4* g4 = (const float4*)(ws + WS_GP + (((size_t)b * 8 + ch) * 256 + tid) * 8);
        float4 a0 = g4[0], a1 = g4[1];
        Svr += a0.x; Svi += a0.y; Tvr += a0.z; Tvi += a0.w;
        Sur += a1.x; Sui += a1.y; Tur += a1.z; Tui += a1.w;
    }
    red[tid] = (Sur * Svr - Sui * Svi) + (Tur * Tvr - Tui * Tvi);
    if (tid < 16) {
        float ar = 0, ai = 0, br = 0, bi = 0;
        for (int ch = 0; ch < 8; ch++) {
            float4 c = *(const float4*)(ws + WS_CS + (((size_t)b * 8 + ch) * 16 + tid) * 4);
            ar += c.x; ai += c.y; br += c.z; bi += c.w;
        }
        red2[tid] = br * ar - bi * ai;
    }
    __syncthreads();
    for (int s = 128; s > 0; s >>= 1) {
        if (tid < s) red[tid] += red[tid + s];
        __syncthreads();
    }
    if (tid == 0) {
        float msum = 0.f;
        for (int i = 0; i < 16; i++) msum += red2[i];
        double MN = 262144.0;
        double mu = (double)msum / MN;
        double sumsq = 0.5 * (double)red[0];
        double var = (sumsq - MN * mu * mu) / (MN - 1.0);
        if (var < 1e-30) var = 1e-30;
        float* stats = ws + WS_STATS;
        stats[b * 2] = (float)mu;
        stats[b * 2 + 1] = (float)(1.0 / sqrt(var));
    }
}

// ---------------------------------------------------------------------------
// k_bmod: fused rank-16 outer product + normalization + base modulation.
__global__ __launch_bounds__(256) void k_bmod(float* __restrict__ ws) {
    const float* mi_s  = ws + WS_MIS;
    const float* mj_s  = ws + WS_MJS;
    const float* baseT = ws + WS_BASET;
    const float* stats = ws + WS_STATS;
    unsigned int* B2T  = (unsigned int*)(ws + WS_B2T);
    int mt = blockIdx.x, nt = blockIdx.y, b = blockIdx.z;
    __shared__ float Ns[16][128];
    __shared__ float Ms[16][128];
    int tid = threadIdx.x, tx = tid & 15, ty = tid >> 4;
    const float* Nb = mj_s + (size_t)b * 16384;
    const float* Mb = mi_s + (size_t)b * 16384;
    int n0 = nt * 64, m0 = mt * 64;
    for (int i = 0; i < 4; i++) {
        int flat = tid + i * 256;
        int col = flat & 63, r = flat >> 6;
        float2 sa = *(const float2*)(Nb + ((size_t)r * 512 + n0 + col) * 2);
        Ns[r][col * 2] = sa.x; Ns[r][col * 2 + 1] = sa.y;
        float2 sb = *(const float2*)(Mb + ((size_t)r * 512 + m0 + col) * 2);
        Ms[r][col * 2] = sb.x; Ms[r][col * 2 + 1] = sb.y;
    }
    __syncthreads();
    float cr[4][4] = {}, ci[4][4] = {};
    for (int r = 0; r < 16; r++) {
        float nr[4], ni[4], mr[4], mi_[4];
        for (int i = 0; i < 4; i++) { nr[i] = Ns[r][(ty * 4 + i) * 2]; ni[i] = Ns[r][(ty * 4 + i) * 2 + 1]; }
        for (int j = 0; j < 4; j++) { mr[j] = Ms[r][(tx + j * 16) * 2]; mi_[j] = Ms[r][(tx + j * 16) * 2 + 1]; }
        for (int i = 0; i < 4; i++)
            for (int j = 0; j < 4; j++) {
                cr[i][j] += nr[i] * mr[j] - ni[i] * mi_[j];
                ci[i][j] += nr[i] * mi_[j] + ni[i] * mr[j];
            }
    }
    float mu = stats[b * 2], rstd = stats[b * 2 + 1];
    unsigned int* Bb = B2T + (size_t)b * 524288;
    for (int i = 0; i < 4; i++) {
        int n = n0 + ty * 4 + i;
        for (int j = 0; j < 4; j++) {
            int m = m0 + tx + j * 16;
            float2 bs = *(const float2*)(baseT + ((size_t)n * 512 + m) * 2);
            float wr = bs.x * (1.f + (cr[i][j] - mu) * rstd);
            float wi = bs.y * (1.f + ci[i][j]);
            Bb[(size_t)(2 * n) * 512 + m]     = pack2bf(wr, -wi);
            Bb[(size_t)(2 * n + 1) * 512 + m] = pack2bf(wi, wr);
        }
    }
}

// ---------------------------------------------------------------------------
// MFMA GEMM, double-buffered single-barrier K-loop.
template <int TM, int TN, bool OUT_BF16>
__global__ __launch_bounds__(256) void k_gemm(const unsigned short* __restrict__ Aall,
                                              const unsigned short* __restrict__ BTall,
                                              void* __restrict__ Call,
                                              const float* __restrict__ td,
                                              const float* __restrict__ rd,
                                              size_t a_bs, size_t bt_bs, size_t c_bs,
                                              int ngl) {
    constexpr int K = 1024;
    constexpr int NK = K / 64;
    constexpr int IT = TM / 32, JT = TN / 32;
    constexpr int STG = (TM + TN) * 64;            // shorts per stage buffer
    constexpr int SMC = OUT_BF16 ? TM * (TN + 8) : 0;
    constexpr int SMEMN = (2 * STG > SMC) ? 2 * STG : SMC;
    __shared__ __align__(16) unsigned short smem[SMEMN];

    const int tid = threadIdx.x;
    const int b = blockIdx.z;
    const unsigned short* A  = Aall  + (size_t)b * a_bs;
    const unsigned short* BT = BTall + (size_t)b * bt_bs;
    const int mBase = blockIdx.y * TM;
    const int nBase = blockIdx.x * TN;
    const int wave = tid >> 6, lane = tid & 63;
    const int wm = wave >> 1, wn = wave & 1;
    const int l15 = lane & 15, q = lane >> 4;

    f32x4 acc[IT][JT];
    for (int i = 0; i < IT; i++)
        for (int j = 0; j < JT; j++) acc[i][j] = (f32x4)0.f;

    auto stage = [&](int k0, int buf) {
        unsigned short* As = smem + buf * STG;
        unsigned short* Bs = As + TM * 64;
#pragma unroll
        for (int p = 0; p < TM / 32; p++) {
            int flat = tid + p * 256;
            int r = flat >> 3, c = flat & 7;
            int gc = (c ^ (r & 7)) << 3;
            load_lds16(A + (size_t)(mBase + r) * K + k0 + gc, &As[flat << 3]);
        }
#pragma unroll
        for (int p = 0; p < TN / 32; p++) {
            int flat = tid + p * 256;
            int r = flat >> 3, c = flat & 7;
            int gc = (c ^ (r & 7)) << 3;
            load_lds16(BT + (size_t)(nBase + r) * K + k0 + gc, &Bs[flat << 3]);
        }
    };

    stage(0, 0);
    for (int kt = 0; kt < NK; kt++) {
        __syncthreads();     // drains vmcnt: tile kt landed; tile kt+1 loads
                             // issued below overlap this iteration's compute
        if (kt + 1 < NK) stage((kt + 1) * 64, (kt + 1) & 1);
        const unsigned short* As = smem + (kt & 1) * STG;
        const unsigned short* Bs = As + TM * 64;
#pragma unroll
        for (int ks = 0; ks < 2; ks++) {
            short8 af[IT], bfr[JT];
#pragma unroll
            for (int t = 0; t < IT; t++) {
                int ra = wm * (TM / 2) + t * 16 + l15;
                int ja = (ks * 4 + q) ^ (ra & 7);
                af[t] = *(const short8*)&As[ra * 64 + ja * 8];
            }
#pragma unroll
            for (int t = 0; t < JT; t++) {
                int rb = wn * (TN / 2) + t * 16 + l15;
                int jb = (ks * 4 + q) ^ (rb & 7);
                bfr[t] = *(const short8*)&Bs[rb * 64 + jb * 8];
            }
#pragma unroll
            for (int i = 0; i < IT; i++)
#pragma unroll
                for (int j = 0; j < JT; j++)
                    acc[i][j] = __builtin_amdgcn_mfma_f32_16x16x32_bf16(af[i], bfr[j], acc[i][j], 0, 0, 0);
        }
    }

    if constexpr (OUT_BF16) {
        __syncthreads();     // Cs aliases the staging buffers
        unsigned short* Cs = smem;
#pragma unroll
        for (int i = 0; i < IT; i++) {
            int row0 = wm * (TM / 2) + i * 16 + q * 4;
#pragma unroll
            for (int j = 0; j < JT; j++) {
                int col = wn * (TN / 2) + j * 16 + l15;
#pragma unroll
                for (int r = 0; r < 4; r++)
                    Cs[(row0 + r) * (TN + 8) + col] = f2bf(acc[i][j][r]);
            }
        }
        __syncthreads();
        unsigned short* C = (unsigned short*)Call + (size_t)b * c_bs;
#pragma unroll
        for (int p = 0; p < TM * TN / 2048; p++) {
            int flat = tid + p * 256;
            int r = flat / (TN / 8), c = flat % (TN / 8);
            short8 v = *(const short8*)&Cs[r * (TN + 8) + c * 8];
            *(short8*)(C + (size_t)(mBase + r) * ngl + nBase + c * 8) = v;
        }
    } else {
        float CC = 0.f;
        for (int c = 0; c < 16; c++) CC += td[2 * c + 1] * rd[2 * c + 1] - td[2 * c] * rd[2 * c];
        float* C = (float*)Call + (size_t)b * c_bs;
#pragma unroll
        for (int i = 0; i < IT; i++) {
            int row0 = mBase + wm * (TM / 2) + i * 16 + q * 4;
#pragma unroll
            for (int j = 0; j < JT; j++) {
                int col = nBase + wn * (TN / 2) + j * 16 + l15;
#pragma unroll
                for (int r = 0; r < 4; r++)
                    C[(size_t)(row0 + r) * ngl + col] = acc[i][j][r] + CC;
            }
        }
    }
}

// ---------------------------------------------------------------------------
extern "C" void kernel_launch(void* const* d_in, const int* in_sizes, int n_in,
                              void* d_out, int out_size, void* d_ws, size_t ws_size,
                              hipStream_t stream) {
    const float* x    = (const float*)d_in[0];
    const float* Wi   = (const float*)d_in[1];
    const float* Wj   = (const float*)d_in[2];
    const float* base = (const float*)d_in[3];
    const float* td   = (const float*)d_in[6];
    const float* rd   = (const float*)d_in[7];
    const float* modi = (const float*)d_in[8];
    const float* modj = (const float*)d_in[9];
    const float* inv  = (const float*)d_in[10];
    const float* mt   = (const float*)d_in[11];
    float* ws  = (float*)d_ws;
    float* out = (float*)d_out;

    unsigned short* A2  = (unsigned short*)(ws + WS_A2);
    unsigned short* B5T = (unsigned short*)(ws + WS_B5T);
    unsigned short* B2T = (unsigned short*)(ws + WS_B2T);
    unsigned short* G1X = (unsigned short*)(ws + WS_G1X);

    k_front<<<1280, 256, 0, stream>>>(Wi, Wj, base, rd, x, mt, inv, modi, modj, ws);
    k_gram1<<<dim3(8, 8), 256, 0, stream>>>(ws);
    k_gram2<<<8, 256, 0, stream>>>(ws);
    k_bmod<<<dim3(8, 8, 8), 256, 0, stream>>>(ws);
    k_gemm<128, 128, true><<<dim3(8, 4, 8), 256, 0, stream>>>(
        A2, B2T, (void*)G1X, td, rd, (size_t)0, (size_t)1048576, (size_t)524288, 1024);
    k_gemm<64, 128, false><<<dim3(4, 8, 8), 256, 0, stream>>>(
        G1X, B5T, (void*)out, td, rd, (size_t)524288, (size_t)0, (size_t)262144, 512);
}

// Round 7
// 131.247 us; speedup vs baseline: 1.3632x; 1.0408x over previous
//
#include <hip/hip_runtime.h>
#include <hip/hip_bf16.h>
#include <math.h>

// Shapes (fixed): B=8, C=16, R=16, M=N=512. K of both real GEMMs = 1024.
//
// Pipeline (5 launches):
//   k_front : [blk 0..767] 32x32 transposes: Wi->A2 bf16, Wj->B5T bf16
//             (*alpha,-im), base->baseT fp32; [blk 768..1279] rank-16
//             factors mi_s/mj_s (fp32) with inline per-block t/(d,e) prep
//   k_gram1 : partial 16x16 Gram matrices per (b, 64-col chunk)  [64 blocks]
//   k_bmod  : inline gram-finish (exact mean/std, ddof=1) + rank-16 outer
//             product + normalize + *baseT -> B2T bf16
//   k_gemm<128,64,true>  : G1X = A2 . B2T^T   (512x1024x1024, bf16 out)
//                          512 blocks @48KB LDS = 2 blocks/CU (overlap)
//   k_gemm<64,128,false> : out = CC + G1X . B5T^T (512x512x1024, fp32 out)
//
// GEMM: both operands staged via global_load_lds width=16, lane-linear dst,
// XOR chunk swizzle (frag ds_read_b128 ~2-way = free), double-buffered
// single-barrier K-loop (barrier vmcnt drain overlaps full compute phase).

#define WS_STATS   1296
#define WS_MIS     4096        // [8][16][512][2] fp32
#define WS_MJS     135168
#define WS_BASET   266240      // [512][512][2] fp32
#define WS_A2      790528      // 512*1024 bf16
#define WS_B5T     1052672     // 512*1024 bf16
#define WS_G1X     1314816     // 8*512*1024 bf16
#define WS_B2T     3411968     // 8*[1024][512] uint (packed bf16 pair)
#define WS_GP      7606272     // gram partials [8][8][256][8] fp32
#define WS_CS      7737344     // colsum partials [8][8][16][4] fp32 ; end 7741440

typedef __attribute__((ext_vector_type(8))) short short8;
typedef __attribute__((ext_vector_type(4))) float f32x4;

__device__ __forceinline__ unsigned short f2bf(float f) {
    unsigned int u = __float_as_uint(f);
    u = (u + 0x7FFFu + ((u >> 16) & 1u)) >> 16;
    return (unsigned short)u;
}
__device__ __forceinline__ unsigned int pack2bf(float a, float b) {
    return (unsigned int)f2bf(a) | ((unsigned int)f2bf(b) << 16);
}
__device__ __forceinline__ void load_lds16(const unsigned short* g, unsigned short* l) {
    __builtin_amdgcn_global_load_lds((const __attribute__((address_space(1))) unsigned int*)g,
                                     (__attribute__((address_space(3))) unsigned int*)l, 16, 0, 0);
}

// ---------------------------------------------------------------------------
// k_front: blocks 0..767 = transposes (mode=blk>>8); blocks 768..1279 = mimj.
__global__ void k_front(const float* __restrict__ Wi, const float* __restrict__ Wj,
                        const float* __restrict__ base, const float* __restrict__ rd,
                        const float* __restrict__ x, const float* __restrict__ mt,
                        const float* __restrict__ inv, const float* __restrict__ mod_i,
                        const float* __restrict__ mod_j, float* __restrict__ ws) {
    __shared__ __align__(16) char shmem[32 * 33 * 8];
    int blk = blockIdx.x;
    int tid = threadIdx.x;
    if (blk < 768) {
        float2(*tile)[33] = (float2(*)[33])shmem;
        int mode = blk >> 8;
        int idx = blk & 255;
        int bx = idx & 15, by = idx >> 4;
        int tx = tid & 31, ty = tid >> 5;
        const float* src = (mode == 0) ? Wi : (mode == 1) ? Wj : base;
        for (int i = 0; i < 4; i++) {
            int rIn = by * 32 + ty + i * 8;
            int cIn = bx * 32 + tx;
            tile[ty + i * 8][tx] = *(const float2*)(src + ((size_t)rIn * 512 + cIn) * 2);
        }
        __syncthreads();
        if (mode == 0) {
            unsigned int* A2u = (unsigned int*)(ws + WS_A2);
            for (int i = 0; i < 4; i++) {
                int rOut = bx * 32 + ty + i * 8;
                int cOut = by * 32 + tx;
                float2 v = tile[tx][ty + i * 8];
                A2u[(size_t)rOut * 512 + cOut] = pack2bf(v.x, v.y);
            }
        } else if (mode == 1) {
            float ar = 0.f, ai = 0.f;
            for (int c = 0; c < 16; c++) { ar -= rd[2 * c]; ai -= rd[2 * c + 1]; }
            unsigned int* B5u = (unsigned int*)(ws + WS_B5T);
            for (int i = 0; i < 4; i++) {
                int rOut = bx * 32 + ty + i * 8;
                int cOut = by * 32 + tx;
                float2 v = tile[tx][ty + i * 8];
                float wr = ar * v.x - ai * v.y;
                float wi = ar * v.y + ai * v.x;
                B5u[(size_t)rOut * 512 + cOut] = pack2bf(wr, -wi);
            }
        } else {
            float* baseT = ws + WS_BASET;
            for (int i = 0; i < 4; i++) {
                int rOut = bx * 32 + ty + i * 8;
                int cOut = by * 32 + tx;
                *(float2*)(baseT + ((size_t)rOut * 512 + cOut) * 2) = tile[tx][ty + i * 8];
            }
        }
    } else {
        float* tb = (float*)shmem;          // 128 floats
        float* deS = (float*)shmem + 128;   // 32 floats
        int blk2 = blk - 768;
        bool isMi = blk2 < 256;
        int id = (isMi ? blk2 : blk2 - 256) * 256 + tid;
        int b = id >> 13, rm = id & 8191;
        if (tid < 128) {
            int k = tid >> 5, l = tid & 31;
            float s = 0.f;
            for (int c = 0; c < 16; c++) s += x[b * 16 + c] * mt[(k * 16 + c) * 32 + l];
            tb[tid] = s;
        }
        __syncthreads();
        if (tid < 16) {
            float i0 = inv[2 * tid], i1 = inv[2 * tid + 1];
            float z0 = tb[32 + 2 * tid], z1 = tb[32 + 2 * tid + 1];
            deS[2 * tid]     = i0 * z0 + i1 * z1;
            deS[2 * tid + 1] = i0 * z1 - i1 * z0;
        }
        __syncthreads();
        if (isMi) {
            float acc0 = 0.f, acc1 = 0.f;
            for (int c = 0; c < 16; c++) {
                const float* p = mod_i + (((size_t)c * 8192) + rm) * 2;
                float A0 = p[0] + tb[2 * c], A1 = p[1] + tb[2 * c + 1];
                float d = deS[2 * c], e = deS[2 * c + 1];
                acc0 += d * A0 - e * A1;
                acc1 += e * A0 + d * A1;
            }
            float* dst = ws + WS_MIS + ((size_t)b * 8192 + rm) * 2;
            dst[0] = acc0; dst[1] = acc1;
        } else {
            float acc0 = 0.f, acc1 = 0.f;
            for (int c = 0; c < 16; c++) {
                const float* p = mod_j + (((size_t)c * 8192) + rm) * 2;
                float A0 = p[0] + tb[64 + 2 * c], A1 = p[1] + tb[64 + 2 * c + 1];
                float z0 = tb[96 + 2 * c], z1 = tb[96 + 2 * c + 1];
                float w0 = -z0 * A0 + z1 * A1;
                float w1 =  z1 * A0 + z0 * A1;
                float i0 = inv[2 * c], i1 = inv[2 * c + 1];
                float den = w0 * w0 + w1 * w1;
                acc0 += (i0 * w0 + i1 * w1) / den;
                acc1 += (i0 * w1 - i1 * w0) / den;
            }
            float* dst = ws + WS_MJS + ((size_t)b * 8192 + rm) * 2;
            dst[0] = acc0; dst[1] = acc1;
        }
    }
}

// ---------------------------------------------------------------------------
// k_gram1: partial Grams over a 64-column chunk. grid (chunk=8, b=8).
__global__ __launch_bounds__(256) void k_gram1(float* __restrict__ ws) {
    __shared__ float2 Vs[16][66];
    __shared__ float2 Us[16][66];
    int ch = blockIdx.x, b = blockIdx.y, tid = threadIdx.x;
    int r = tid >> 4, r2 = tid & 15;
    const float2* V = (const float2*)(ws + WS_MIS + (size_t)b * 16384);
    const float2* U = (const float2*)(ws + WS_MJS + (size_t)b * 16384);
    int c0 = ch * 64;
    for (int p = 0; p < 4; p++) {
        int f = tid + p * 256;
        int rr = f >> 6, mm = f & 63;
        Vs[rr][mm] = V[rr * 512 + c0 + mm];
        Us[rr][mm] = U[rr * 512 + c0 + mm];
    }
    __syncthreads();
    float Svr = 0, Svi = 0, Tvr = 0, Tvi = 0;
    float Sur = 0, Sui = 0, Tur = 0, Tui = 0;
    float ar = 0, ai = 0, br = 0, bi = 0;
    for (int mm = 0; mm < 64; mm++) {
        float2 v1 = Vs[r][mm], v2 = Vs[r2][mm];
        float2 u1 = Us[r][mm], u2 = Us[r2][mm];
        Svr += v1.x * v2.x - v1.y * v2.y;  Svi += v1.x * v2.y + v1.y * v2.x;
        Tvr += v1.x * v2.x + v1.y * v2.y;  Tvi += v1.y * v2.x - v1.x * v2.y;
        Sur += u1.x * u2.x - u1.y * u2.y;  Sui += u1.x * u2.y + u1.y * u2.x;
        Tur += u1.x * u2.x + u1.y * u2.y;  Tui += u1.y * u2.x - u1.x * u2.y;
        if (r2 == 0) { ar += v1.x; ai += v1.y; br += u1.x; bi += u1.y; }
    }
    float4* g4 = (float4*)(ws + WS_GP + (((size_t)b * 8 + ch) * 256 + tid) * 8);
    g4[0] = make_float4(Svr, Svi, Tvr, Tvi);
    g4[1] = make_float4(Sur, Sui, Tur, Tui);
    if (r2 == 0)
        *(float4*)(ws + WS_CS + (((size_t)b * 8 + ch) * 16 + r) * 4) =
            make_float4(ar, ai, br, bi);
}

// ---------------------------------------------------------------------------
// k_bmod: inline gram-finish (mu, 1/std) + rank-16 outer product + normalize
// + *baseT -> B2T bf16. Each block redundantly reduces its batch's Gram
// partials (16 KB, L2-hot) — removes the serial k_gram2 launch.
__global__ __launch_bounds__(256) void k_bmod(float* __restrict__ ws) {
    const float* mi_s  = ws + WS_MIS;
    const float* mj_s  = ws + WS_MJS;
    const float* baseT = ws + WS_BASET;
    unsigned int* B2T  = (unsigned int*)(ws + WS_B2T);
    int mt = blockIdx.x, nt = blockIdx.y, b = blockIdx.z;
    __shared__ float Ns[16][128];
    __shared__ float Ms[16][128];
    __shared__ float red[256];
    __shared__ float red2[16];
    __shared__ float sStat[2];
    int tid = threadIdx.x, tx = tid & 15, ty = tid >> 4;

    // ---- gram finish: mu, rstd for batch b ----
    {
        float Svr = 0, Svi = 0, Tvr = 0, Tvi = 0;
        float Sur = 0, Sui = 0, Tur = 0, Tui = 0;
        for (int ch = 0; ch < 8; ch++) {
            const float4* g4 = (const float4*)(ws + WS_GP + (((size_t)b * 8 + ch) * 256 + tid) * 8);
            float4 a0 = g4[0], a1 = g4[1];
            Svr += a0.x; Svi += a0.y; Tvr += a0.z; Tvi += a0.w;
            Sur += a1.x; Sui += a1.y; Tur += a1.z; Tui += a1.w;
        }
        red[tid] = (Sur * Svr - Sui * Svi) + (Tur * Tvr - Tui * Tvi);
        if (tid < 16) {
            float ar = 0, ai = 0, br = 0, bi = 0;
            for (int ch = 0; ch < 8; ch++) {
                float4 c = *(const float4*)(ws + WS_CS + (((size_t)b * 8 + ch) * 16 + tid) * 4);
                ar += c.x; ai += c.y; br += c.z; bi += c.w;
            }
            red2[tid] = br * ar - bi * ai;
        }
        __syncthreads();
        for (int s = 128; s > 0; s >>= 1) {
            if (tid < s) red[tid] += red[tid + s];
            __syncthreads();
        }
        if (tid == 0) {
            float msum = 0.f;
            for (int i = 0; i < 16; i++) msum += red2[i];
            double MN = 262144.0;
            double mu = (double)msum / MN;
            double sumsq = 0.5 * (double)red[0];
            double var = (sumsq - MN * mu * mu) / (MN - 1.0);
            if (var < 1e-30) var = 1e-30;
            sStat[0] = (float)mu;
            sStat[1] = (float)(1.0 / sqrt(var));
        }
    }

    const float* Nb = mj_s + (size_t)b * 16384;
    const float* Mb = mi_s + (size_t)b * 16384;
    int n0 = nt * 64, m0 = mt * 64;
    for (int i = 0; i < 4; i++) {
        int flat = tid + i * 256;
        int col = flat & 63, r = flat >> 6;
        float2 sa = *(const float2*)(Nb + ((size_t)r * 512 + n0 + col) * 2);
        Ns[r][col * 2] = sa.x; Ns[r][col * 2 + 1] = sa.y;
        float2 sb = *(const float2*)(Mb + ((size_t)r * 512 + m0 + col) * 2);
        Ms[r][col * 2] = sb.x; Ms[r][col * 2 + 1] = sb.y;
    }
    __syncthreads();
    float cr[4][4] = {}, ci[4][4] = {};
    for (int r = 0; r < 16; r++) {
        float nr[4], ni[4], mr[4], mi_[4];
        for (int i = 0; i < 4; i++) { nr[i] = Ns[r][(ty * 4 + i) * 2]; ni[i] = Ns[r][(ty * 4 + i) * 2 + 1]; }
        for (int j = 0; j < 4; j++) { mr[j] = Ms[r][(tx + j * 16) * 2]; mi_[j] = Ms[r][(tx + j * 16) * 2 + 1]; }
        for (int i = 0; i < 4; i++)
            for (int j = 0; j < 4; j++) {
                cr[i][j] += nr[i] * mr[j] - ni[i] * mi_[j];
                ci[i][j] += nr[i] * mi_[j] + ni[i] * mr[j];
            }
    }
    float mu = sStat[0], rstd = sStat[1];
    unsigned int* Bb = B2T + (size_t)b * 524288;
    for (int i = 0; i < 4; i++) {
        int n = n0 + ty * 4 + i;
        for (int j = 0; j < 4; j++) {
            int m = m0 + tx + j * 16;
            float2 bs = *(const float2*)(baseT + ((size_t)n * 512 + m) * 2);
            float wr = bs.x * (1.f + (cr[i][j] - mu) * rstd);
            float wi = bs.y * (1.f + ci[i][j]);
            Bb[(size_t)(2 * n) * 512 + m]     = pack2bf(wr, -wi);
            Bb[(size_t)(2 * n + 1) * 512 + m] = pack2bf(wi, wr);
        }
    }
}

// ---------------------------------------------------------------------------
// MFMA GEMM, double-buffered single-barrier K-loop.
template <int TM, int TN, bool OUT_BF16>
__global__ __launch_bounds__(256) void k_gemm(const unsigned short* __restrict__ Aall,
                                              const unsigned short* __restrict__ BTall,
                                              void* __restrict__ Call,
                                              const float* __restrict__ td,
                                              const float* __restrict__ rd,
                                              size_t a_bs, size_t bt_bs, size_t c_bs,
                                              int ngl) {
    constexpr int K = 1024;
    constexpr int NK = K / 64;
    constexpr int IT = TM / 32, JT = TN / 32;
    constexpr int STG = (TM + TN) * 64;            // shorts per stage buffer
    constexpr int SMC = OUT_BF16 ? TM * (TN + 8) : 0;
    constexpr int SMEMN = (2 * STG > SMC) ? 2 * STG : SMC;
    __shared__ __align__(16) unsigned short smem[SMEMN];

    const int tid = threadIdx.x;
    const int b = blockIdx.z;
    const unsigned short* A  = Aall  + (size_t)b * a_bs;
    const unsigned short* BT = BTall + (size_t)b * bt_bs;
    const int mBase = blockIdx.y * TM;
    const int nBase = blockIdx.x * TN;
    const int wave = tid >> 6, lane = tid & 63;
    const int wm = wave >> 1, wn = wave & 1;
    const int l15 = lane & 15, q = lane >> 4;

    f32x4 acc[IT][JT];
    for (int i = 0; i < IT; i++)
        for (int j = 0; j < JT; j++) acc[i][j] = (f32x4)0.f;

    auto stage = [&](int k0, int buf) {
        unsigned short* As = smem + buf * STG;
        unsigned short* Bs = As + TM * 64;
#pragma unroll
        for (int p = 0; p < TM / 32; p++) {
            int flat = tid + p * 256;
            int r = flat >> 3, c = flat & 7;
            int gc = (c ^ (r & 7)) << 3;
            load_lds16(A + (size_t)(mBase + r) * K + k0 + gc, &As[flat << 3]);
        }
#pragma unroll
        for (int p = 0; p < TN / 32; p++) {
            int flat = tid + p * 256;
            int r = flat >> 3, c = flat & 7;
            int gc = (c ^ (r & 7)) << 3;
            load_lds16(BT + (size_t)(nBase + r) * K + k0 + gc, &Bs[flat << 3]);
        }
    };

    stage(0, 0);
    for (int kt = 0; kt < NK; kt++) {
        __syncthreads();     // drains vmcnt: tile kt landed; tile kt+1 loads
                             // issued below overlap this iteration's compute
        if (kt + 1 < NK) stage((kt + 1) * 64, (kt + 1) & 1);
        const unsigned short* As = smem + (kt & 1) * STG;
        const unsigned short* Bs = As + TM * 64;
#pragma unroll
        for (int ks = 0; ks < 2; ks++) {
            short8 af[IT], bfr[JT];
#pragma unroll
            for (int t = 0; t < IT; t++) {
                int ra = wm * (TM / 2) + t * 16 + l15;
                int ja = (ks * 4 + q) ^ (ra & 7);
                af[t] = *(const short8*)&As[ra * 64 + ja * 8];
            }
#pragma unroll
            for (int t = 0; t < JT; t++) {
                int rb = wn * (TN / 2) + t * 16 + l15;
                int jb = (ks * 4 + q) ^ (rb & 7);
                bfr[t] = *(const short8*)&Bs[rb * 64 + jb * 8];
            }
#pragma unroll
            for (int i = 0; i < IT; i++)
#pragma unroll
                for (int j = 0; j < JT; j++)
                    acc[i][j] = __builtin_amdgcn_mfma_f32_16x16x32_bf16(af[i], bfr[j], acc[i][j], 0, 0, 0);
        }
    }

    if constexpr (OUT_BF16) {
        __syncthreads();     // Cs aliases the staging buffers
        unsigned short* Cs = smem;
#pragma unroll
        for (int i = 0; i < IT; i++) {
            int row0 = wm * (TM / 2) + i * 16 + q * 4;
#pragma unroll
            for (int j = 0; j < JT; j++) {
                int col = wn * (TN / 2) + j * 16 + l15;
#pragma unroll
                for (int r = 0; r < 4; r++)
                    Cs[(row0 + r) * (TN + 8) + col] = f2bf(acc[i][j][r]);
            }
        }
        __syncthreads();
        unsigned short* C = (unsigned short*)Call + (size_t)b * c_bs;
#pragma unroll
        for (int p = 0; p < TM * TN / 2048; p++) {
            int flat = tid + p * 256;
            int r = flat / (TN / 8), c = flat % (TN / 8);
            short8 v = *(const short8*)&Cs[r * (TN + 8) + c * 8];
            *(short8*)(C + (size_t)(mBase + r) * ngl + nBase + c * 8) = v;
        }
    } else {
        float CC = 0.f;
        for (int c = 0; c < 16; c++) CC += td[2 * c + 1] * rd[2 * c + 1] - td[2 * c] * rd[2 * c];
        float* C = (float*)Call + (size_t)b * c_bs;
#pragma unroll
        for (int i = 0; i < IT; i++) {
            int row0 = mBase + wm * (TM / 2) + i * 16 + q * 4;
#pragma unroll
            for (int j = 0; j < JT; j++) {
                int col = nBase + wn * (TN / 2) + j * 16 + l15;
#pragma unroll
                for (int r = 0; r < 4; r++)
                    C[(size_t)(row0 + r) * ngl + col] = acc[i][j][r] + CC;
            }
        }
    }
}

// ---------------------------------------------------------------------------
extern "C" void kernel_launch(void* const* d_in, const int* in_sizes, int n_in,
                              void* d_out, int out_size, void* d_ws, size_t ws_size,
                              hipStream_t stream) {
    const float* x    = (const float*)d_in[0];
    const float* Wi   = (const float*)d_in[1];
    const float* Wj   = (const float*)d_in[2];
    const float* base = (const float*)d_in[3];
    const float* td   = (const float*)d_in[6];
    const float* rd   = (const float*)d_in[7];
    const float* modi = (const float*)d_in[8];
    const float* modj = (const float*)d_in[9];
    const float* inv  = (const float*)d_in[10];
    const float* mt   = (const float*)d_in[11];
    float* ws  = (float*)d_ws;
    float* out = (float*)d_out;

    unsigned short* A2  = (unsigned short*)(ws + WS_A2);
    unsigned short* B5T = (unsigned short*)(ws + WS_B5T);
    unsigned short* B2T = (unsigned short*)(ws + WS_B2T);
    unsigned short* G1X = (unsigned short*)(ws + WS_G1X);

    k_front<<<1280, 256, 0, stream>>>(Wi, Wj, base, rd, x, mt, inv, modi, modj, ws);
    k_gram1<<<dim3(8, 8), 256, 0, stream>>>(ws);
    k_bmod<<<dim3(8, 8, 8), 256, 0, stream>>>(ws);
    k_gemm<128, 64, true><<<dim3(16, 4, 8), 256, 0, stream>>>(
        A2, B2T, (void*)G1X, td, rd, (size_t)0, (size_t)1048576, (size_t)524288, 1024);
    k_gemm<64, 128, false><<<dim3(4, 8, 8), 256, 0, stream>>>(
        G1X, B5T, (void*)out, td, rd, (size_t)524288, (size_t)0, (size_t)262144, 512);
}